// Round 1
// baseline (2535.301 us; speedup 1.0000x reference)
//
#include <hip/hip_runtime.h>
#include <math.h>

#define B_ 4
#define T_ 1024
#define E_ 1024
#define H_ 16
#define HD_ 64

constexpr float SCALE_ = 0.125f;              // HD^-0.5
constexpr float PI_F = 3.14159265358979323846f;

constexpr size_t EW  = (size_t)E_ * E_;       // 1M
constexpr size_t BTE = (size_t)B_ * T_ * E_;  // 4M
constexpr size_t BTT = (size_t)B_ * T_ * T_;  // 4M

// ---------------------------------------------------------------- weights
__global__ __launch_bounds__(256) void wgen(const float* __restrict__ lm,
                                            const float* __restrict__ ph,
                                            float* __restrict__ wr,
                                            float* __restrict__ wi) {
    size_t i = (size_t)blockIdx.x * 256 + threadIdx.x;
    float m = expf(lm[i]);
    float s, c;
    sincosf(ph[i], &s, &c);
    wr[i] = m * c;
    wi[i] = m * s;
}

// ---------------------------------------------------------------- geodesic bias table
__global__ __launch_bounds__(256) void geodist(const float* __restrict__ lat,
                                               const float* __restrict__ lon,
                                               float* __restrict__ ld) {
    size_t idx = (size_t)blockIdx.x * 256 + threadIdx.x;   // over B*T*T
    int k = (int)(idx & (T_ - 1));
    int q = (int)((idx >> 10) & (T_ - 1));
    int b = (int)(idx >> 20);
    float la1 = (lat[b * T_ + q] - 90.f) * (PI_F / 180.f);
    float la2 = (lat[b * T_ + k] - 90.f) * (PI_F / 180.f);
    float lo1 = lon[b * T_ + q] * (PI_F / 180.f);
    float lo2 = lon[b * T_ + k] * (PI_F / 180.f);
    float sdla = sinf((la2 - la1) * 0.5f);
    float sdlo = sinf((lo2 - lo1) * 0.5f);
    float a = sdla * sdla + cosf(la1) * cosf(la2) * sdlo * sdlo;
    a = fminf(fmaxf(a, 0.f), 1.f);
    float dd = 2.f * asinf(sqrtf(a)) * (180.f / PI_F);
    ld[idx] = log1pf(dd);
}

// ---------------------------------------------------------------- complex GEMM (NT)
// C_r = A_r B_r^T - A_i B_i^T + bias_r ; C_i = A_r B_i^T + A_i B_r^T + bias_i
// A: [M][K] row-major, B: [N][K] row-major.
constexpr int GM = 64, GN = 64, GK = 16;

__global__ __launch_bounds__(256) void cgemm_nt(const float* __restrict__ Ar,
                                                const float* __restrict__ Ai,
                                                const float* __restrict__ Br,
                                                const float* __restrict__ Bi,
                                                const float* __restrict__ bmag,
                                                const float* __restrict__ bphase,
                                                float* __restrict__ Cr,
                                                float* __restrict__ Ci,
                                                int M, int N, int K) {
    __shared__ float sAr[GK][GM + 4], sAi[GK][GM + 4];
    __shared__ float sBr[GK][GN + 4], sBi[GK][GN + 4];

    const int tid = threadIdx.x;
    const int bm = blockIdx.x * GM;
    const int bn = blockIdx.y * GN;
    const int tm = (tid >> 4) << 2;   // 0..60
    const int tn = (tid & 15) << 2;   // 0..60
    const int lr = tid >> 2;          // 0..63
    const int lc = (tid & 3) << 2;    // 0,4,8,12

    float accr[4][4] = {}, acci[4][4] = {};

    for (int k0 = 0; k0 < K; k0 += GK) {
        float4 a_r = *(const float4*)(Ar + (size_t)(bm + lr) * K + k0 + lc);
        float4 a_i = *(const float4*)(Ai + (size_t)(bm + lr) * K + k0 + lc);
        float4 b_r = *(const float4*)(Br + (size_t)(bn + lr) * K + k0 + lc);
        float4 b_i = *(const float4*)(Bi + (size_t)(bn + lr) * K + k0 + lc);
        __syncthreads();
        sAr[lc + 0][lr] = a_r.x; sAr[lc + 1][lr] = a_r.y; sAr[lc + 2][lr] = a_r.z; sAr[lc + 3][lr] = a_r.w;
        sAi[lc + 0][lr] = a_i.x; sAi[lc + 1][lr] = a_i.y; sAi[lc + 2][lr] = a_i.z; sAi[lc + 3][lr] = a_i.w;
        sBr[lc + 0][lr] = b_r.x; sBr[lc + 1][lr] = b_r.y; sBr[lc + 2][lr] = b_r.z; sBr[lc + 3][lr] = b_r.w;
        sBi[lc + 0][lr] = b_i.x; sBi[lc + 1][lr] = b_i.y; sBi[lc + 2][lr] = b_i.z; sBi[lc + 3][lr] = b_i.w;
        __syncthreads();

#pragma unroll
        for (int kk = 0; kk < GK; ++kk) {
            const float4 ar4 = *(const float4*)&sAr[kk][tm];
            const float4 ai4 = *(const float4*)&sAi[kk][tm];
            const float4 br4 = *(const float4*)&sBr[kk][tn];
            const float4 bi4 = *(const float4*)&sBi[kk][tn];
            const float arv[4] = {ar4.x, ar4.y, ar4.z, ar4.w};
            const float aiv[4] = {ai4.x, ai4.y, ai4.z, ai4.w};
            const float brv[4] = {br4.x, br4.y, br4.z, br4.w};
            const float biv[4] = {bi4.x, bi4.y, bi4.z, bi4.w};
#pragma unroll
            for (int m = 0; m < 4; ++m)
#pragma unroll
                for (int n = 0; n < 4; ++n) {
                    accr[m][n] = fmaf(arv[m], brv[n], accr[m][n]);
                    accr[m][n] = fmaf(-aiv[m], biv[n], accr[m][n]);
                    acci[m][n] = fmaf(arv[m], biv[n], acci[m][n]);
                    acci[m][n] = fmaf(aiv[m], brv[n], acci[m][n]);
                }
        }
    }

#pragma unroll
    for (int n = 0; n < 4; ++n) {
        const int gn = bn + tn + n;
        float bm_ = bmag[gn], bp_ = bphase[gn];
        float sb, cb;
        sincosf(bp_, &sb, &cb);
        const float br_ = bm_ * cb, bi_ = bm_ * sb;
#pragma unroll
        for (int m = 0; m < 4; ++m) {
            const size_t o = (size_t)(bm + tm + m) * N + gn;
            Cr[o] = accr[m][n] + br_;
            Ci[o] = acci[m][n] + bi_;
        }
    }
}

// ---------------------------------------------------------------- RoPE (in place on q,k r/i)
__global__ __launch_bounds__(256) void rope(float* __restrict__ qr, float* __restrict__ qi,
                                            float* __restrict__ kr, float* __restrict__ ki) {
    int idx = blockIdx.x * 256 + threadIdx.x;   // B*T*H*32
    int j = idx & 31;
    int h = (idx >> 5) & (H_ - 1);
    int t = (idx >> 9) & (T_ - 1);
    int b = idx >> 19;
    float invf = expf(-(2.f * j / 64.f) * 9.210340371976184f);   // 10000^(-2j/64)
    float f = (float)t * invf;
    float s, c;
    sincosf(f, &s, &c);
    size_t base = ((size_t)(b * T_ + t)) * E_ + h * HD_ + j;
    float x1, x2;
    x1 = qr[base]; x2 = qr[base + 32];
    qr[base] = x1 * c - x2 * s; qr[base + 32] = x2 * c + x1 * s;
    x1 = qi[base]; x2 = qi[base + 32];
    qi[base] = x1 * c - x2 * s; qi[base + 32] = x2 * c + x1 * s;
    x1 = kr[base]; x2 = kr[base + 32];
    kr[base] = x1 * c - x2 * s; kr[base + 32] = x2 * c + x1 * s;
    x1 = ki[base]; x2 = ki[base + 32];
    ki[base] = x1 * c - x2 * s; ki[base + 32] = x2 * c + x1 * s;
}

// ---------------------------------------------------------------- flash attention
// block = (qt, h, b); 256 threads; 64-q x 64-k tiles, online softmax.
__global__ __launch_bounds__(256) void attn(const float* __restrict__ qr, const float* __restrict__ qi,
                                            const float* __restrict__ kr, const float* __restrict__ ki,
                                            const float* __restrict__ vr, const float* __restrict__ vi,
                                            const float* __restrict__ ld,
                                            const float* __restrict__ dsc, const float* __restrict__ dof,
                                            float* __restrict__ outr, float* __restrict__ outi) {
    __shared__ float sQr[64][68], sQi[64][68];   // [d][q]
    __shared__ float sKr[64][68], sKi[64][68];   // [d][k]
    __shared__ float sVr[64][68], sVi[64][68];   // [k][d]
    __shared__ float sP[64][68];                 // [k][q]

    const int qt = blockIdx.x, h = blockIdx.y, b = blockIdx.z;
    const int tid = threadIdx.x;
    const int ty = tid >> 4;          // 0..15 -> q group
    const int tx = tid & 15;          // 0..15 -> k / d group
    const int q0 = ty << 2;
    const int k0w = tx << 2;
    const int d0 = tx << 2;

    const float ds = dsc[h], doff = dof[h];

    // stage Q tile transposed [d][q]
#pragma unroll
    for (int it = 0; it < 4; ++it) {
        int f = it * 256 + tid;
        int r = f >> 4;
        int dc = (f & 15) << 2;
        size_t g = ((size_t)(b * T_ + qt * 64 + r)) * E_ + h * HD_ + dc;
        float4 x = *(const float4*)(qr + g);
        float4 y = *(const float4*)(qi + g);
        sQr[dc + 0][r] = x.x; sQr[dc + 1][r] = x.y; sQr[dc + 2][r] = x.z; sQr[dc + 3][r] = x.w;
        sQi[dc + 0][r] = y.x; sQi[dc + 1][r] = y.y; sQi[dc + 2][r] = y.z; sQi[dc + 3][r] = y.w;
    }

    float accR[4][4] = {}, accI[4][4] = {};
    float m_run[4], l_run[4];
#pragma unroll
    for (int m = 0; m < 4; ++m) { m_run[m] = -INFINITY; l_run[m] = 0.f; }

    for (int kt = 0; kt <= qt; ++kt) {
        __syncthreads();   // previous iteration finished reading sK/sV/sP (also orders Q staging)
        // stage K (transposed) and V (natural)
#pragma unroll
        for (int it = 0; it < 4; ++it) {
            int f = it * 256 + tid;
            int r = f >> 4;
            int dc = (f & 15) << 2;
            size_t g = ((size_t)(b * T_ + kt * 64 + r)) * E_ + h * HD_ + dc;
            float4 xr = *(const float4*)(kr + g);
            float4 xi = *(const float4*)(ki + g);
            float4 yr = *(const float4*)(vr + g);
            float4 yi = *(const float4*)(vi + g);
            sKr[dc + 0][r] = xr.x; sKr[dc + 1][r] = xr.y; sKr[dc + 2][r] = xr.z; sKr[dc + 3][r] = xr.w;
            sKi[dc + 0][r] = xi.x; sKi[dc + 1][r] = xi.y; sKi[dc + 2][r] = xi.z; sKi[dc + 3][r] = xi.w;
            *(float4*)&sVr[r][dc] = yr;
            *(float4*)&sVi[r][dc] = yi;
        }
        __syncthreads();

        // QK^T micro-tile 4x4
        float s_[4][4] = {};
#pragma unroll
        for (int d = 0; d < 64; ++d) {
            const float4 q_r = *(const float4*)&sQr[d][q0];
            const float4 q_i = *(const float4*)&sQi[d][q0];
            const float4 k_r = *(const float4*)&sKr[d][k0w];
            const float4 k_i = *(const float4*)&sKi[d][k0w];
            const float qrv[4] = {q_r.x, q_r.y, q_r.z, q_r.w};
            const float qiv[4] = {q_i.x, q_i.y, q_i.z, q_i.w};
            const float krv[4] = {k_r.x, k_r.y, k_r.z, k_r.w};
            const float kiv[4] = {k_i.x, k_i.y, k_i.z, k_i.w};
#pragma unroll
            for (int m = 0; m < 4; ++m)
#pragma unroll
                for (int n = 0; n < 4; ++n) {
                    s_[m][n] = fmaf(qrv[m], krv[n], s_[m][n]);
                    s_[m][n] = fmaf(qiv[m], kiv[n], s_[m][n]);
                }
        }

        // scale + bias + causal mask
        const int qg0 = qt * 64 + q0;
        const int kg0 = kt * 64 + k0w;
#pragma unroll
        for (int m = 0; m < 4; ++m) {
            const size_t ldrow = ((size_t)b * T_ + (qg0 + m)) * T_ + kg0;
#pragma unroll
            for (int n = 0; n < 4; ++n) {
                float sv = s_[m][n] * SCALE_ + ds * ld[ldrow + n] + doff;
                if (kg0 + n > qg0 + m) sv = -1.0e9f;
                s_[m][n] = sv;
            }
        }

        // online softmax
#pragma unroll
        for (int m = 0; m < 4; ++m) {
            float mt = fmaxf(fmaxf(s_[m][0], s_[m][1]), fmaxf(s_[m][2], s_[m][3]));
            mt = fmaxf(mt, __shfl_xor(mt, 1));
            mt = fmaxf(mt, __shfl_xor(mt, 2));
            mt = fmaxf(mt, __shfl_xor(mt, 4));
            mt = fmaxf(mt, __shfl_xor(mt, 8));
            const float mnew = fmaxf(m_run[m], mt);
            const float sc = __expf(m_run[m] - mnew);
            float rs = 0.f;
#pragma unroll
            for (int n = 0; n < 4; ++n) {
                const float p = __expf(s_[m][n] - mnew);
                s_[m][n] = p;
                rs += p;
            }
            rs += __shfl_xor(rs, 1);
            rs += __shfl_xor(rs, 2);
            rs += __shfl_xor(rs, 4);
            rs += __shfl_xor(rs, 8);
            l_run[m] = l_run[m] * sc + rs;
            m_run[m] = mnew;
#pragma unroll
            for (int n = 0; n < 4; ++n) { accR[m][n] *= sc; accI[m][n] *= sc; }
        }

        // share P as [k][q]
#pragma unroll
        for (int m = 0; m < 4; ++m)
#pragma unroll
            for (int n = 0; n < 4; ++n) sP[k0w + n][q0 + m] = s_[m][n];
        __syncthreads();

        // PV micro-tile 4x4 (q x d)
#pragma unroll
        for (int k = 0; k < 64; ++k) {
            const float4 p4 = *(const float4*)&sP[k][q0];
            const float4 v_r = *(const float4*)&sVr[k][d0];
            const float4 v_i = *(const float4*)&sVi[k][d0];
            const float pv[4] = {p4.x, p4.y, p4.z, p4.w};
            const float vrv[4] = {v_r.x, v_r.y, v_r.z, v_r.w};
            const float viv[4] = {v_i.x, v_i.y, v_i.z, v_i.w};
#pragma unroll
            for (int m = 0; m < 4; ++m)
#pragma unroll
                for (int n = 0; n < 4; ++n) {
                    accR[m][n] = fmaf(pv[m], vrv[n], accR[m][n]);
                    accI[m][n] = fmaf(pv[m], viv[n], accI[m][n]);
                }
        }
    }

    // write normalized output
#pragma unroll
    for (int m = 0; m < 4; ++m) {
        const float inv = 1.0f / l_run[m];
        const size_t row = ((size_t)(b * T_ + qt * 64 + q0 + m)) * E_ + h * HD_ + d0;
        float4 o_r, o_i;
        o_r.x = accR[m][0] * inv; o_r.y = accR[m][1] * inv; o_r.z = accR[m][2] * inv; o_r.w = accR[m][3] * inv;
        o_i.x = accI[m][0] * inv; o_i.y = accI[m][1] * inv; o_i.z = accI[m][2] * inv; o_i.w = accI[m][3] * inv;
        *(float4*)(outr + row) = o_r;
        *(float4*)(outi + row) = o_i;
    }
}

// ---------------------------------------------------------------- launch
extern "C" void kernel_launch(void* const* d_in, const int* in_sizes, int n_in,
                              void* d_out, int out_size, void* d_ws, size_t ws_size,
                              hipStream_t stream) {
    const float* x_r  = (const float*)d_in[0];
    const float* x_i  = (const float*)d_in[1];
    const float* lat  = (const float*)d_in[2];
    const float* lon  = (const float*)d_in[3];
    const float* q_lm = (const float*)d_in[4];
    const float* q_ph = (const float*)d_in[5];
    const float* q_bm = (const float*)d_in[6];
    const float* q_bp = (const float*)d_in[7];
    const float* k_lm = (const float*)d_in[8];
    const float* k_ph = (const float*)d_in[9];
    const float* k_bm = (const float*)d_in[10];
    const float* k_bp = (const float*)d_in[11];
    const float* v_lm = (const float*)d_in[12];
    const float* v_ph = (const float*)d_in[13];
    const float* v_bm = (const float*)d_in[14];
    const float* v_bp = (const float*)d_in[15];
    const float* o_lm = (const float*)d_in[16];
    const float* o_ph = (const float*)d_in[17];
    const float* o_bm = (const float*)d_in[18];
    const float* o_bp = (const float*)d_in[19];
    const float* dsc  = (const float*)d_in[20];
    const float* dof  = (const float*)d_in[21];

    float* ws = (float*)d_ws;
    float* wqr = ws + 0 * EW;
    float* wqi = ws + 1 * EW;
    float* wkr = ws + 2 * EW;
    float* wki = ws + 3 * EW;
    float* wvr = ws + 4 * EW;
    float* wvi = ws + 5 * EW;
    float* wor = ws + 6 * EW;
    float* woi = ws + 7 * EW;
    float* qr  = ws + 8 * EW + 0 * BTE;
    float* qi  = ws + 8 * EW + 1 * BTE;
    float* kr  = ws + 8 * EW + 2 * BTE;
    float* ki  = ws + 8 * EW + 3 * BTE;
    float* vr  = ws + 8 * EW + 4 * BTE;
    float* vi  = ws + 8 * EW + 5 * BTE;
    float* otr = ws + 8 * EW + 6 * BTE;
    float* oti = ws + 8 * EW + 7 * BTE;
    float* ldt = ws + 8 * EW + 8 * BTE;   // B*T*T

    // weights
    wgen<<<EW / 256, 256, 0, stream>>>(q_lm, q_ph, wqr, wqi);
    wgen<<<EW / 256, 256, 0, stream>>>(k_lm, k_ph, wkr, wki);
    wgen<<<EW / 256, 256, 0, stream>>>(v_lm, v_ph, wvr, wvi);
    wgen<<<EW / 256, 256, 0, stream>>>(o_lm, o_ph, wor, woi);

    // geodesic log-dist table
    geodist<<<BTT / 256, 256, 0, stream>>>(lat, lon, ldt);

    // projections
    const int M = B_ * T_, N = E_, K = E_;
    dim3 ggrid(M / GM, N / GN);
    cgemm_nt<<<ggrid, 256, 0, stream>>>(x_r, x_i, wqr, wqi, q_bm, q_bp, qr, qi, M, N, K);
    cgemm_nt<<<ggrid, 256, 0, stream>>>(x_r, x_i, wkr, wki, k_bm, k_bp, kr, ki, M, N, K);
    cgemm_nt<<<ggrid, 256, 0, stream>>>(x_r, x_i, wvr, wvi, v_bm, v_bp, vr, vi, M, N, K);

    // rope on q,k
    rope<<<(B_ * T_ * H_ * 32) / 256, 256, 0, stream>>>(qr, qi, kr, ki);

    // attention
    dim3 agrid(T_ / 64, H_, B_);
    attn<<<agrid, 256, 0, stream>>>(qr, qi, kr, ki, vr, vi, ldt, dsc, dof, otr, oti);

    // output projection -> d_out (yr then yi)
    float* yr = (float*)d_out;
    float* yi = (float*)d_out + BTE;
    cgemm_nt<<<ggrid, 256, 0, stream>>>(otr, oti, wor, woi, o_bm, o_bp, yr, yi, M, N, K);
}

// Round 3
// 737.076 us; speedup vs baseline: 3.4397x; 3.4397x over previous
//
#include <hip/hip_runtime.h>
#include <math.h>

#define B_ 4
#define T_ 1024
#define E_ 1024
#define H_ 16
#define HD_ 64

constexpr float SCALE_ = 0.125f;              // HD^-0.5
constexpr float PI_F = 3.14159265358979323846f;

constexpr size_t BTE = (size_t)B_ * T_ * E_;  // 4M
constexpr size_t BTT = (size_t)B_ * T_ * T_;  // 4M
constexpr int M_ = B_ * T_;                   // 4096
constexpr int KC_ = 2 * E_;                   // 2048 (concat r|i)

typedef __attribute__((ext_vector_type(8))) short bf16x8;
typedef __attribute__((ext_vector_type(4))) float f32x4;

__device__ __forceinline__ short f2bf(float f) {
    unsigned int u = __float_as_uint(f);
    unsigned int r = (u + 0x7fffu + ((u >> 16) & 1u)) >> 16;
    return (short)r;
}
__device__ __forceinline__ float bf2f(short s) {
    return __uint_as_float(((unsigned int)(unsigned short)s) << 16);
}
__device__ __forceinline__ void fsplit(float v, short& h, short& l) {
    short hh = f2bf(v);
    h = hh;
    l = f2bf(v - bf2f(hh));
}
__device__ __forceinline__ void gl_lds16(const void* g, void* l) {
    __builtin_amdgcn_global_load_lds(
        (const __attribute__((address_space(1))) unsigned int*)g,
        (__attribute__((address_space(3))) unsigned int*)l, 16, 0, 0);
}

// ---------------------------------------------------------------- stacked bf16 weights (single)
// W [2048][2048]: rows 0..1023 real out: [wr | -wi]; rows 1024..: [wi | wr]
__global__ __launch_bounds__(256) void wgen(const float* __restrict__ lm,
                                            const float* __restrict__ ph,
                                            short* __restrict__ W) {
    int idx = blockIdx.x * 256 + threadIdx.x;   // over E*E
    int n = idx >> 10, k = idx & 1023;
    float m = expf(lm[idx]);
    float s, c;
    sincosf(ph[idx], &s, &c);
    float wr = m * c, wi = m * s;
    size_t r0 = (size_t)n * KC_;
    size_t r1 = (size_t)(n + 1024) * KC_;
    W[r0 + k]        = f2bf(wr);
    W[r0 + 1024 + k] = f2bf(-wi);
    W[r1 + k]        = f2bf(wi);
    W[r1 + 1024 + k] = f2bf(wr);
}

// ---------------------------------------------------------------- stacked bf16 weights (hi/lo split)
__global__ __launch_bounds__(256) void wgen_split(const float* __restrict__ lm,
                                                  const float* __restrict__ ph,
                                                  short* __restrict__ Wh,
                                                  short* __restrict__ Wl) {
    int idx = blockIdx.x * 256 + threadIdx.x;
    int n = idx >> 10, k = idx & 1023;
    float m = expf(lm[idx]);
    float s, c;
    sincosf(ph[idx], &s, &c);
    float wr = m * c, wi = m * s;
    size_t o0 = (size_t)n * KC_ + k;
    size_t o1 = (size_t)n * KC_ + 1024 + k;
    size_t o2 = (size_t)(n + 1024) * KC_ + k;
    size_t o3 = (size_t)(n + 1024) * KC_ + 1024 + k;
    short h, l;
    fsplit(wr,  h, l); Wh[o0] = h; Wl[o0] = l;
    fsplit(-wi, h, l); Wh[o1] = h; Wl[o1] = l;
    fsplit(wi,  h, l); Wh[o2] = h; Wl[o2] = l;
    fsplit(wr,  h, l); Wh[o3] = h; Wl[o3] = l;
}

// ---------------------------------------------------------------- x concat -> bf16 hi/lo
__global__ __launch_bounds__(256) void xcat_split(const float* __restrict__ xr,
                                                  const float* __restrict__ xi,
                                                  short* __restrict__ xh,
                                                  short* __restrict__ xl) {
    size_t idx = (size_t)blockIdx.x * 256 + threadIdx.x;  // BTE
    size_t m = idx >> 10, k = idx & 1023;
    short h, l;
    fsplit(xr[idx], h, l);
    xh[m * KC_ + k] = h; xl[m * KC_ + k] = l;
    fsplit(xi[idx], h, l);
    xh[m * KC_ + 1024 + k] = h; xl[m * KC_ + 1024 + k] = l;
}

// ---------------------------------------------------------------- geodesic bias table
__global__ __launch_bounds__(256) void geodist(const float* __restrict__ lat,
                                               const float* __restrict__ lon,
                                               float* __restrict__ ld) {
    size_t idx = (size_t)blockIdx.x * 256 + threadIdx.x;   // over B*T*T
    int k = (int)(idx & (T_ - 1));
    int q = (int)((idx >> 10) & (T_ - 1));
    int b = (int)(idx >> 20);
    float la1 = (lat[b * T_ + q] - 90.f) * (PI_F / 180.f);
    float la2 = (lat[b * T_ + k] - 90.f) * (PI_F / 180.f);
    float lo1 = lon[b * T_ + q] * (PI_F / 180.f);
    float lo2 = lon[b * T_ + k] * (PI_F / 180.f);
    float sdla = sinf((la2 - la1) * 0.5f);
    float sdlo = sinf((lo2 - lo1) * 0.5f);
    float a = sdla * sdla + cosf(la1) * cosf(la2) * sdlo * sdlo;
    a = fminf(fmaxf(a, 0.f), 1.f);
    float dd = 2.f * asinf(sqrtf(a)) * (180.f / PI_F);
    ld[idx] = log1pf(dd);
}

// ---------------------------------------------------------------- split-bf16 Q/K GEMM + fused RoPE
// C = (Ah+Al)(Wh+Wl)^T (3 terms) + bias, then RoPE, then hi/lo split store
// in head-concat layout: out[row][h*128 + d + 64*imag].
__global__ __launch_bounds__(256) void cgemm_qk(const short* __restrict__ Ah,
                                                const short* __restrict__ Al,
                                                const short* __restrict__ Wh,
                                                const short* __restrict__ Wl,
                                                const float* __restrict__ bmag,
                                                const float* __restrict__ bphase,
                                                short* __restrict__ Qh,
                                                short* __restrict__ Ql) {
    __shared__ short sAh[128 * 32], sAl[128 * 32];
    __shared__ short sBh[128 * 32], sBl[128 * 32];

    const int tid = threadIdx.x;
    const int w = tid >> 6, l = tid & 63;
    const int wm = w >> 1, wn = w & 1;
    const int wl = l & 15, g = l >> 4;

    int id = blockIdx.y * 32 + blockIdx.x;     // nwg = 512
    int swz = (id & 7) * 64 + (id >> 3);
    const int bm = (swz & 31) * 128;
    const int bn = (swz >> 5) * 128;

    f32x4 acc[4][4];
#pragma unroll
    for (int m = 0; m < 4; ++m)
#pragma unroll
        for (int n = 0; n < 4; ++n) acc[m][n] = (f32x4){0.f, 0.f, 0.f, 0.f};

    for (int k0 = 0; k0 < KC_; k0 += 32) {
        __syncthreads();
#pragma unroll
        for (int i = 0; i < 2; ++i) {
            int chunk = (w * 2 + i) * 64 + l;
            int row = chunk >> 2, kc = chunk & 3;
            size_t ga = (size_t)(bm + row) * KC_ + k0 + kc * 8;
            size_t gb = (size_t)(bn + row) * KC_ + k0 + kc * 8;
            gl_lds16(Ah + ga, sAh + (w * 2 + i) * 64 * 8);
            gl_lds16(Al + ga, sAl + (w * 2 + i) * 64 * 8);
            gl_lds16(Wh + gb, sBh + (w * 2 + i) * 64 * 8);
            gl_lds16(Wl + gb, sBl + (w * 2 + i) * 64 * 8);
        }
        __syncthreads();

        bf16x8 afh[4], afl[4], bfh[4], bfl[4];
#pragma unroll
        for (int m = 0; m < 4; ++m) {
            afh[m] = *(const bf16x8*)&sAh[(wm * 64 + m * 16 + wl) * 32 + g * 8];
            afl[m] = *(const bf16x8*)&sAl[(wm * 64 + m * 16 + wl) * 32 + g * 8];
        }
#pragma unroll
        for (int n = 0; n < 4; ++n) {
            bfh[n] = *(const bf16x8*)&sBh[(wn * 64 + n * 16 + wl) * 32 + g * 8];
            bfl[n] = *(const bf16x8*)&sBl[(wn * 64 + n * 16 + wl) * 32 + g * 8];
        }
#pragma unroll
        for (int m = 0; m < 4; ++m)
#pragma unroll
            for (int n = 0; n < 4; ++n) {
                acc[m][n] = __builtin_amdgcn_mfma_f32_16x16x32_bf16(afh[m], bfh[n], acc[m][n], 0, 0, 0);
                acc[m][n] = __builtin_amdgcn_mfma_f32_16x16x32_bf16(afh[m], bfl[n], acc[m][n], 0, 0, 0);
                acc[m][n] = __builtin_amdgcn_mfma_f32_16x16x32_bf16(afl[m], bfh[n], acc[m][n], 0, 0, 0);
            }
    }

    // bias add
#pragma unroll
    for (int n = 0; n < 4; ++n) {
        const int col = bn + wn * 64 + n * 16 + wl;
        const int ch = col & 1023;
        float sb, cb;
        sincosf(bphase[ch], &sb, &cb);
        const float bias = bmag[ch] * (col < 1024 ? cb : sb);
#pragma unroll
        for (int m = 0; m < 4; ++m)
#pragma unroll
            for (int r = 0; r < 4; ++r) acc[m][n][r] += bias;
    }

    // fused RoPE: pairs (n, n+2) <-> (e, e+32) within the 64-block; freq j = n*16+wl
#pragma unroll
    for (int n = 0; n < 2; ++n) {
        const int j = n * 16 + wl;
        const float invf = expf(-(2.f * j / 64.f) * 9.210340371976184f);
#pragma unroll
        for (int m = 0; m < 4; ++m)
#pragma unroll
            for (int r = 0; r < 4; ++r) {
                const int row = bm + wm * 64 + m * 16 + g * 4 + r;
                const float th = (float)(row & 1023) * invf;
                float s_, c_;
                sincosf(th, &s_, &c_);
                const float x1 = acc[m][n][r], x2 = acc[m][n + 2][r];
                acc[m][n][r]     = x1 * c_ - x2 * s_;
                acc[m][n + 2][r] = x2 * c_ + x1 * s_;
            }
    }

    // split store, head-concat layout
#pragma unroll
    for (int n = 0; n < 4; ++n) {
        const int col = bn + wn * 64 + n * 16 + wl;
        const int ch = col & 1023;
        const int off = (ch >> 6) * 128 + (ch & 63) + ((col >= 1024) ? 64 : 0);
#pragma unroll
        for (int m = 0; m < 4; ++m)
#pragma unroll
            for (int r = 0; r < 4; ++r) {
                const int row = bm + wm * 64 + m * 16 + g * 4 + r;
                short h_, l_;
                fsplit(acc[m][n][r], h_, l_);
                Qh[(size_t)row * KC_ + off] = h_;
                Ql[(size_t)row * KC_ + off] = l_;
            }
    }
}

// ---------------------------------------------------------------- single-bf16 MFMA GEMM (V, O)
// mode 0: bf16 head-concat out; mode 1: fp32 outr/outi
__global__ __launch_bounds__(256) void cgemm_mfma(const short* __restrict__ A,
                                                  const short* __restrict__ W,
                                                  const float* __restrict__ bmag,
                                                  const float* __restrict__ bphase,
                                                  short* __restrict__ outbf,
                                                  float* __restrict__ outr,
                                                  float* __restrict__ outi,
                                                  int mode) {
    __shared__ short sA[128 * 32];
    __shared__ short sB[128 * 32];

    const int tid = threadIdx.x;
    const int w = tid >> 6, l = tid & 63;
    const int wm = w >> 1, wn = w & 1;
    const int wl = l & 15, g = l >> 4;

    int id = blockIdx.y * 32 + blockIdx.x;
    int swz = (id & 7) * 64 + (id >> 3);
    const int bm = (swz & 31) * 128;
    const int bn = (swz >> 5) * 128;

    f32x4 acc[4][4];
#pragma unroll
    for (int m = 0; m < 4; ++m)
#pragma unroll
        for (int n = 0; n < 4; ++n) acc[m][n] = (f32x4){0.f, 0.f, 0.f, 0.f};

    for (int k0 = 0; k0 < KC_; k0 += 32) {
        __syncthreads();
#pragma unroll
        for (int i = 0; i < 2; ++i) {
            int chunk = (w * 2 + i) * 64 + l;
            int row = chunk >> 2, kc = chunk & 3;
            gl_lds16(A + (size_t)(bm + row) * KC_ + k0 + kc * 8, sA + (w * 2 + i) * 64 * 8);
            gl_lds16(W + (size_t)(bn + row) * KC_ + k0 + kc * 8, sB + (w * 2 + i) * 64 * 8);
        }
        __syncthreads();

        bf16x8 af[4], bfr[4];
#pragma unroll
        for (int m = 0; m < 4; ++m)
            af[m] = *(const bf16x8*)&sA[(wm * 64 + m * 16 + wl) * 32 + g * 8];
#pragma unroll
        for (int n = 0; n < 4; ++n)
            bfr[n] = *(const bf16x8*)&sB[(wn * 64 + n * 16 + wl) * 32 + g * 8];
#pragma unroll
        for (int m = 0; m < 4; ++m)
#pragma unroll
            for (int n = 0; n < 4; ++n)
                acc[m][n] = __builtin_amdgcn_mfma_f32_16x16x32_bf16(af[m], bfr[n], acc[m][n], 0, 0, 0);
    }

#pragma unroll
    for (int n = 0; n < 4; ++n) {
        const int col = bn + wn * 64 + n * 16 + wl;
        const int ch = col & 1023;
        float sb, cb;
        sincosf(bphase[ch], &sb, &cb);
        const float bias = bmag[ch] * (col < 1024 ? cb : sb);
#pragma unroll
        for (int m = 0; m < 4; ++m) {
#pragma unroll
            for (int r = 0; r < 4; ++r) {
                const int row = bm + wm * 64 + m * 16 + g * 4 + r;
                const float v = acc[m][n][r] + bias;
                if (mode == 0) {
                    const int hh = ch >> 6, d = ch & 63;
                    outbf[(size_t)row * KC_ + hh * 128 + d + ((col >= 1024) ? 64 : 0)] = f2bf(v);
                } else {
                    if (col < 1024) outr[(size_t)row * E_ + col] = v;
                    else            outi[(size_t)row * E_ + (col - 1024)] = v;
                }
            }
        }
    }
}

// ---------------------------------------------------------------- MFMA flash attention, split-bf16 QK^T
__global__ __launch_bounds__(256) void attn_split(const short* __restrict__ qh,
                                                  const short* __restrict__ ql,
                                                  const short* __restrict__ kh,
                                                  const short* __restrict__ kl,
                                                  const short* __restrict__ vc,
                                                  const float* __restrict__ ld,
                                                  const float* __restrict__ dsc,
                                                  const float* __restrict__ dof,
                                                  short* __restrict__ otc) {
    __shared__ short sKh[64 * 128];       // swizzled 16B chunks
    __shared__ short sKl[64 * 128];
    __shared__ short sV[2][64 * 66];      // [comp][d][66] (V transposed)
    __shared__ short sP[4][16 * 68];      // per-wave P [qlocal][68]

    const int qt = blockIdx.x, h = blockIdx.y, b = blockIdx.z;
    const int tid = threadIdx.x;
    const int w = tid >> 6, l = tid & 63;
    const int wl = l & 15, g = l >> 4;

    const float dsch = dsc[h], dofh = dof[h];

    // Q hi/lo fragments: rows q = qt*64 + w*16 + wl
    bf16x8 aqh[4], aql[4];
    {
        const size_t qbase = ((size_t)(b * T_) + qt * 64 + w * 16 + wl) * KC_ + h * 128;
#pragma unroll
        for (int ks = 0; ks < 4; ++ks) {
            aqh[ks] = *(const bf16x8*)(qh + qbase + ks * 32 + g * 8);
            aql[ks] = *(const bf16x8*)(ql + qbase + ks * 32 + g * 8);
        }
    }

    f32x4 accR[4], accI[4];
#pragma unroll
    for (int nb = 0; nb < 4; ++nb) {
        accR[nb] = (f32x4){0.f, 0.f, 0.f, 0.f};
        accI[nb] = (f32x4){0.f, 0.f, 0.f, 0.f};
    }
    float m_run[4], l_run[4];
#pragma unroll
    for (int r = 0; r < 4; ++r) { m_run[r] = -3.0e38f; l_run[r] = 0.f; }

    for (int kt = 0; kt <= qt; ++kt) {
        __syncthreads();

        // stage K hi/lo: linear dest, inverse-swizzled per-lane source
#pragma unroll
        for (int i = 0; i < 4; ++i) {
            int chunk = (w * 4 + i) * 64 + l;
            int row = chunk >> 4;
            int c8 = (chunk & 15) ^ ((row & 7) << 1);
            size_t src = ((size_t)(b * T_) + kt * 64 + row) * KC_ + h * 128 + c8 * 8;
            gl_lds16(kh + src, sKh + (w * 4 + i) * 64 * 8);
            gl_lds16(kl + src, sKl + (w * 4 + i) * 64 * 8);
        }
        // stage V transposed
        {
            const short* vrow = vc + ((size_t)(b * T_) + kt * 64 + l) * KC_ + h * 128;
#pragma unroll
            for (int comp = 0; comp < 2; ++comp)
#pragma unroll
                for (int half = 0; half < 2; ++half) {
                    int d0 = w * 8 + half * 32;
                    bf16x8 v8 = *(const bf16x8*)(vrow + comp * 64 + d0);
#pragma unroll
                    for (int j = 0; j < 8; ++j) sV[comp][(d0 + j) * 66 + l] = v8[j];
                }
        }
        __syncthreads();

        // QK^T split: per fragment hh + hl + lh
        f32x4 s[4];
#pragma unroll
        for (int nb = 0; nb < 4; ++nb) s[nb] = (f32x4){0.f, 0.f, 0.f, 0.f};
#pragma unroll
        for (int nb = 0; nb < 4; ++nb) {
            const int ktl = nb * 16 + wl;
#pragma unroll
            for (int ks = 0; ks < 4; ++ks) {
                const int pc8 = (ks * 4 + g) ^ ((ktl & 7) << 1);
                const bf16x8 bkh = *(const bf16x8*)&sKh[ktl * 128 + pc8 * 8];
                const bf16x8 bkl = *(const bf16x8*)&sKl[ktl * 128 + pc8 * 8];
                s[nb] = __builtin_amdgcn_mfma_f32_16x16x32_bf16(aqh[ks], bkh, s[nb], 0, 0, 0);
                s[nb] = __builtin_amdgcn_mfma_f32_16x16x32_bf16(aqh[ks], bkl, s[nb], 0, 0, 0);
                s[nb] = __builtin_amdgcn_mfma_f32_16x16x32_bf16(aql[ks], bkh, s[nb], 0, 0, 0);
            }
        }

        // scale + geo bias + causal mask
        const int qg0 = qt * 64 + w * 16 + g * 4;
        const int kg0 = kt * 64;
#pragma unroll
        for (int nb = 0; nb < 4; ++nb) {
            const int kg = kg0 + nb * 16 + wl;
            const float* ldp = ld + ((size_t)b * T_ + qg0) * T_ + kg;
#pragma unroll
            for (int r = 0; r < 4; ++r) {
                float sv = s[nb][r] * SCALE_ + dsch * ldp[(size_t)r * T_] + dofh;
                if (kt == qt && kg > qg0 + r) sv = -1.0e9f;
                s[nb][r] = sv;
            }
        }

        // online softmax
#pragma unroll
        for (int r = 0; r < 4; ++r) {
            float mt = fmaxf(fmaxf(s[0][r], s[1][r]), fmaxf(s[2][r], s[3][r]));
            mt = fmaxf(mt, __shfl_xor(mt, 1));
            mt = fmaxf(mt, __shfl_xor(mt, 2));
            mt = fmaxf(mt, __shfl_xor(mt, 4));
            mt = fmaxf(mt, __shfl_xor(mt, 8));
            const float mnew = fmaxf(m_run[r], mt);
            const float sc = __expf(m_run[r] - mnew);
            m_run[r] = mnew;
            float rs = 0.f;
#pragma unroll
            for (int nb = 0; nb < 4; ++nb) {
                const float p = __expf(s[nb][r] - mnew);
                s[nb][r] = p;
                rs += p;
            }
            rs += __shfl_xor(rs, 1);
            rs += __shfl_xor(rs, 2);
            rs += __shfl_xor(rs, 4);
            rs += __shfl_xor(rs, 8);
            l_run[r] = l_run[r] * sc + rs;
#pragma unroll
            for (int nb = 0; nb < 4; ++nb) { accR[nb][r] *= sc; accI[nb][r] *= sc; }
        }

        // P -> LDS (wave-private), then PV
#pragma unroll
        for (int nb = 0; nb < 4; ++nb)
#pragma unroll
            for (int r = 0; r < 4; ++r)
                sP[w][(g * 4 + r) * 68 + nb * 16 + wl] = f2bf(s[nb][r]);

        bf16x8 ap[2];
#pragma unroll
        for (int ks = 0; ks < 2; ++ks)
            ap[ks] = *(const bf16x8*)&sP[w][wl * 68 + ks * 32 + g * 8];
#pragma unroll
        for (int nb = 0; nb < 4; ++nb) {
#pragma unroll
            for (int ks = 0; ks < 2; ++ks) {
                const bf16x8 bvr = *(const bf16x8*)&sV[0][(nb * 16 + wl) * 66 + ks * 32 + g * 8];
                const bf16x8 bvi = *(const bf16x8*)&sV[1][(nb * 16 + wl) * 66 + ks * 32 + g * 8];
                accR[nb] = __builtin_amdgcn_mfma_f32_16x16x32_bf16(ap[ks], bvr, accR[nb], 0, 0, 0);
                accI[nb] = __builtin_amdgcn_mfma_f32_16x16x32_bf16(ap[ks], bvi, accI[nb], 0, 0, 0);
            }
        }
    }

    // epilogue
    float inv[4];
#pragma unroll
    for (int r = 0; r < 4; ++r) inv[r] = 1.0f / l_run[r];
#pragma unroll
    for (int nb = 0; nb < 4; ++nb) {
#pragma unroll
        for (int r = 0; r < 4; ++r) {
            const int q = qt * 64 + w * 16 + g * 4 + r;
            const int d = nb * 16 + wl;
            const size_t base = ((size_t)(b * T_) + q) * KC_ + h * 64 + d;
            otc[base] = f2bf(accR[nb][r] * inv[r]);
            otc[base + 1024] = f2bf(accI[nb][r] * inv[r]);
        }
    }
}

// ---------------------------------------------------------------- launch
extern "C" void kernel_launch(void* const* d_in, const int* in_sizes, int n_in,
                              void* d_out, int out_size, void* d_ws, size_t ws_size,
                              hipStream_t stream) {
    const float* x_r  = (const float*)d_in[0];
    const float* x_i  = (const float*)d_in[1];
    const float* lat  = (const float*)d_in[2];
    const float* lon  = (const float*)d_in[3];
    const float* q_lm = (const float*)d_in[4];
    const float* q_ph = (const float*)d_in[5];
    const float* q_bm = (const float*)d_in[6];
    const float* q_bp = (const float*)d_in[7];
    const float* k_lm = (const float*)d_in[8];
    const float* k_ph = (const float*)d_in[9];
    const float* k_bm = (const float*)d_in[10];
    const float* k_bp = (const float*)d_in[11];
    const float* v_lm = (const float*)d_in[12];
    const float* v_ph = (const float*)d_in[13];
    const float* v_bm = (const float*)d_in[14];
    const float* v_bp = (const float*)d_in[15];
    const float* o_lm = (const float*)d_in[16];
    const float* o_ph = (const float*)d_in[17];
    const float* o_bm = (const float*)d_in[18];
    const float* o_bp = (const float*)d_in[19];
    const float* dsc  = (const float*)d_in[20];
    const float* dof  = (const float*)d_in[21];

    char* ws = (char*)d_ws;
    const size_t MB = 1024u * 1024u;
    short* Wv  = (short*)(ws + 0 * MB);     // 8 MB
    short* Wo  = (short*)(ws + 8 * MB);     // 8 MB
    short* Wqh = (short*)(ws + 16 * MB);    // 8 MB
    short* Wql = (short*)(ws + 24 * MB);
    short* Wkh = (short*)(ws + 32 * MB);
    short* Wkl = (short*)(ws + 40 * MB);
    short* xch = (short*)(ws + 48 * MB);    // 16 MB
    short* xcl = (short*)(ws + 64 * MB);    // 16 MB
    short* qhh = (short*)(ws + 80 * MB);    // 16 MB
    short* qll = (short*)(ws + 96 * MB);
    short* khh = (short*)(ws + 112 * MB);
    short* kll = (short*)(ws + 128 * MB);
    short* vcb = (short*)(ws + 144 * MB);   // 16 MB
    short* otc = (short*)(ws + 160 * MB);   // 16 MB
    float* ldt = (float*)(ws + 176 * MB);   // 16 MB

    wgen_split<<<(E_ * E_) / 256, 256, 0, stream>>>(q_lm, q_ph, Wqh, Wql);
    wgen_split<<<(E_ * E_) / 256, 256, 0, stream>>>(k_lm, k_ph, Wkh, Wkl);
    wgen<<<(E_ * E_) / 256, 256, 0, stream>>>(v_lm, v_ph, Wv);
    wgen<<<(E_ * E_) / 256, 256, 0, stream>>>(o_lm, o_ph, Wo);
    xcat_split<<<BTE / 256, 256, 0, stream>>>(x_r, x_i, xch, xcl);
    geodist<<<BTT / 256, 256, 0, stream>>>(lat, lon, ldt);

    dim3 ggrid(M_ / 128, KC_ / 128);
    cgemm_qk<<<ggrid, 256, 0, stream>>>(xch, xcl, Wqh, Wql, q_bm, q_bp, qhh, qll);
    cgemm_qk<<<ggrid, 256, 0, stream>>>(xch, xcl, Wkh, Wkl, k_bm, k_bp, khh, kll);
    cgemm_mfma<<<ggrid, 256, 0, stream>>>(xch, Wv, v_bm, v_bp, vcb, nullptr, nullptr, 0);

    dim3 agrid(T_ / 64, H_, B_);
    attn_split<<<agrid, 256, 0, stream>>>(qhh, qll, khh, kll, vcb, ldt, dsc, dof, otc);

    float* yr = (float*)d_out;
    float* yi = (float*)d_out + BTE;
    cgemm_mfma<<<ggrid, 256, 0, stream>>>(otc, Wo, o_bm, o_bp, nullptr, yr, yi, 1);
}

// Round 4
// 649.270 us; speedup vs baseline: 3.9048x; 1.1352x over previous
//
#include <hip/hip_runtime.h>
#include <math.h>

#define B_ 4
#define T_ 1024
#define E_ 1024
#define H_ 16
#define HD_ 64

constexpr float SCALE_ = 0.125f;              // HD^-0.5
constexpr float PI_F = 3.14159265358979323846f;

constexpr size_t BTE = (size_t)B_ * T_ * E_;  // 4M
constexpr size_t BTT = (size_t)B_ * T_ * T_;  // 4M
constexpr int M_ = B_ * T_;                   // 4096
constexpr int KC_ = 2 * E_;                   // 2048 (concat r|i)

typedef __attribute__((ext_vector_type(8))) short bf16x8;
typedef __attribute__((ext_vector_type(4))) float f32x4;

__device__ __forceinline__ short f2bf(float f) {
    unsigned int u = __float_as_uint(f);
    unsigned int r = (u + 0x7fffu + ((u >> 16) & 1u)) >> 16;
    return (short)r;
}
__device__ __forceinline__ float bf2f(short s) {
    return __uint_as_float(((unsigned int)(unsigned short)s) << 16);
}
__device__ __forceinline__ void fsplit(float v, short& h, short& l) {
    short hh = f2bf(v);
    h = hh;
    l = f2bf(v - bf2f(hh));
}
__device__ __forceinline__ void gl_lds16(const void* g, void* l) {
    __builtin_amdgcn_global_load_lds(
        (const __attribute__((address_space(1))) unsigned int*)g,
        (__attribute__((address_space(3))) unsigned int*)l, 16, 0, 0);
}

// ---------------------------------------------------------------- stacked bf16 weights (single)
__global__ __launch_bounds__(256) void wgen(const float* __restrict__ lm,
                                            const float* __restrict__ ph,
                                            short* __restrict__ W) {
    int idx = blockIdx.x * 256 + threadIdx.x;   // over E*E
    int n = idx >> 10, k = idx & 1023;
    float m = expf(lm[idx]);
    float s, c;
    sincosf(ph[idx], &s, &c);
    float wr = m * c, wi = m * s;
    size_t r0 = (size_t)n * KC_;
    size_t r1 = (size_t)(n + 1024) * KC_;
    W[r0 + k]        = f2bf(wr);
    W[r0 + 1024 + k] = f2bf(-wi);
    W[r1 + k]        = f2bf(wi);
    W[r1 + 1024 + k] = f2bf(wr);
}

// ---------------------------------------------------------------- stacked bf16 weights (hi/lo split)
__global__ __launch_bounds__(256) void wgen_split(const float* __restrict__ lm,
                                                  const float* __restrict__ ph,
                                                  short* __restrict__ Wh,
                                                  short* __restrict__ Wl) {
    int idx = blockIdx.x * 256 + threadIdx.x;
    int n = idx >> 10, k = idx & 1023;
    float m = expf(lm[idx]);
    float s, c;
    sincosf(ph[idx], &s, &c);
    float wr = m * c, wi = m * s;
    size_t o0 = (size_t)n * KC_ + k;
    size_t o1 = (size_t)n * KC_ + 1024 + k;
    size_t o2 = (size_t)(n + 1024) * KC_ + k;
    size_t o3 = (size_t)(n + 1024) * KC_ + 1024 + k;
    short h, l;
    fsplit(wr,  h, l); Wh[o0] = h; Wl[o0] = l;
    fsplit(-wi, h, l); Wh[o1] = h; Wl[o1] = l;
    fsplit(wi,  h, l); Wh[o2] = h; Wl[o2] = l;
    fsplit(wr,  h, l); Wh[o3] = h; Wl[o3] = l;
}

// ---------------------------------------------------------------- x concat -> bf16 hi/lo
__global__ __launch_bounds__(256) void xcat_split(const float* __restrict__ xr,
                                                  const float* __restrict__ xi,
                                                  short* __restrict__ xh,
                                                  short* __restrict__ xl) {
    size_t idx = (size_t)blockIdx.x * 256 + threadIdx.x;  // BTE
    size_t m = idx >> 10, k = idx & 1023;
    short h, l;
    fsplit(xr[idx], h, l);
    xh[m * KC_ + k] = h; xl[m * KC_ + k] = l;
    fsplit(xi[idx], h, l);
    xh[m * KC_ + 1024 + k] = h; xl[m * KC_ + 1024 + k] = l;
}

// ---------------------------------------------------------------- geodesic bias table (bf16)
__global__ __launch_bounds__(256) void geodist(const float* __restrict__ lat,
                                               const float* __restrict__ lon,
                                               short* __restrict__ ld) {
    size_t idx = (size_t)blockIdx.x * 256 + threadIdx.x;   // over B*T*T
    int k = (int)(idx & (T_ - 1));
    int q = (int)((idx >> 10) & (T_ - 1));
    int b = (int)(idx >> 20);
    float la1 = (lat[b * T_ + q] - 90.f) * (PI_F / 180.f);
    float la2 = (lat[b * T_ + k] - 90.f) * (PI_F / 180.f);
    float lo1 = lon[b * T_ + q] * (PI_F / 180.f);
    float lo2 = lon[b * T_ + k] * (PI_F / 180.f);
    float sdla = sinf((la2 - la1) * 0.5f);
    float sdlo = sinf((lo2 - lo1) * 0.5f);
    float a = sdla * sdla + cosf(la1) * cosf(la2) * sdlo * sdlo;
    a = fminf(fmaxf(a, 0.f), 1.f);
    float dd = 2.f * asinf(sqrtf(a)) * (180.f / PI_F);
    ld[idx] = f2bf(log1pf(dd));
}

// ---------------------------------------------------------------- split-bf16 Q/K GEMM + fused RoPE
__global__ __launch_bounds__(256) void cgemm_qk(const short* __restrict__ Ah,
                                                const short* __restrict__ Al,
                                                const short* __restrict__ Wh,
                                                const short* __restrict__ Wl,
                                                const float* __restrict__ bmag,
                                                const float* __restrict__ bphase,
                                                short* __restrict__ Qh,
                                                short* __restrict__ Ql) {
    __shared__ short sAh[128 * 32], sAl[128 * 32];
    __shared__ short sBh[128 * 32], sBl[128 * 32];

    const int tid = threadIdx.x;
    const int w = tid >> 6, l = tid & 63;
    const int wm = w >> 1, wn = w & 1;
    const int wl = l & 15, g = l >> 4;

    int id = blockIdx.y * 32 + blockIdx.x;     // nwg = 512
    int swz = (id & 7) * 64 + (id >> 3);
    const int bm = (swz & 31) * 128;
    const int bn = (swz >> 5) * 128;

    f32x4 acc[4][4];
#pragma unroll
    for (int m = 0; m < 4; ++m)
#pragma unroll
        for (int n = 0; n < 4; ++n) acc[m][n] = (f32x4){0.f, 0.f, 0.f, 0.f};

    for (int k0 = 0; k0 < KC_; k0 += 32) {
        __syncthreads();
#pragma unroll
        for (int i = 0; i < 2; ++i) {
            int chunk = (w * 2 + i) * 64 + l;
            int row = chunk >> 2, kc = chunk & 3;
            size_t ga = (size_t)(bm + row) * KC_ + k0 + kc * 8;
            size_t gb = (size_t)(bn + row) * KC_ + k0 + kc * 8;
            gl_lds16(Ah + ga, sAh + (w * 2 + i) * 64 * 8);
            gl_lds16(Al + ga, sAl + (w * 2 + i) * 64 * 8);
            gl_lds16(Wh + gb, sBh + (w * 2 + i) * 64 * 8);
            gl_lds16(Wl + gb, sBl + (w * 2 + i) * 64 * 8);
        }
        __syncthreads();

        bf16x8 afh[4], afl[4], bfh[4], bfl[4];
#pragma unroll
        for (int m = 0; m < 4; ++m) {
            afh[m] = *(const bf16x8*)&sAh[(wm * 64 + m * 16 + wl) * 32 + g * 8];
            afl[m] = *(const bf16x8*)&sAl[(wm * 64 + m * 16 + wl) * 32 + g * 8];
        }
#pragma unroll
        for (int n = 0; n < 4; ++n) {
            bfh[n] = *(const bf16x8*)&sBh[(wn * 64 + n * 16 + wl) * 32 + g * 8];
            bfl[n] = *(const bf16x8*)&sBl[(wn * 64 + n * 16 + wl) * 32 + g * 8];
        }
#pragma unroll
        for (int m = 0; m < 4; ++m)
#pragma unroll
            for (int n = 0; n < 4; ++n) {
                acc[m][n] = __builtin_amdgcn_mfma_f32_16x16x32_bf16(afh[m], bfh[n], acc[m][n], 0, 0, 0);
                acc[m][n] = __builtin_amdgcn_mfma_f32_16x16x32_bf16(afh[m], bfl[n], acc[m][n], 0, 0, 0);
                acc[m][n] = __builtin_amdgcn_mfma_f32_16x16x32_bf16(afl[m], bfh[n], acc[m][n], 0, 0, 0);
            }
    }

    // bias add
#pragma unroll
    for (int n = 0; n < 4; ++n) {
        const int col = bn + wn * 64 + n * 16 + wl;
        const int ch = col & 1023;
        float sb, cb;
        sincosf(bphase[ch], &sb, &cb);
        const float bias = bmag[ch] * (col < 1024 ? cb : sb);
#pragma unroll
        for (int m = 0; m < 4; ++m)
#pragma unroll
            for (int r = 0; r < 4; ++r) acc[m][n][r] += bias;
    }

    // fused RoPE: pairs (n, n+2) <-> (e, e+32); freq j = n*16+wl
#pragma unroll
    for (int n = 0; n < 2; ++n) {
        const int j = n * 16 + wl;
        const float invf = expf(-(2.f * j / 64.f) * 9.210340371976184f);
#pragma unroll
        for (int m = 0; m < 4; ++m)
#pragma unroll
            for (int r = 0; r < 4; ++r) {
                const int row = bm + wm * 64 + m * 16 + g * 4 + r;
                const float th = (float)(row & 1023) * invf;
                float s_, c_;
                sincosf(th, &s_, &c_);
                const float x1 = acc[m][n][r], x2 = acc[m][n + 2][r];
                acc[m][n][r]     = x1 * c_ - x2 * s_;
                acc[m][n + 2][r] = x2 * c_ + x1 * s_;
            }
    }

    // split store, head-concat layout
#pragma unroll
    for (int n = 0; n < 4; ++n) {
        const int col = bn + wn * 64 + n * 16 + wl;
        const int ch = col & 1023;
        const int off = (ch >> 6) * 128 + (ch & 63) + ((col >= 1024) ? 64 : 0);
#pragma unroll
        for (int m = 0; m < 4; ++m)
#pragma unroll
            for (int r = 0; r < 4; ++r) {
                const int row = bm + wm * 64 + m * 16 + g * 4 + r;
                short h_, l_;
                fsplit(acc[m][n][r], h_, l_);
                Qh[(size_t)row * KC_ + off] = h_;
                Ql[(size_t)row * KC_ + off] = l_;
            }
    }
}

// ---------------------------------------------------------------- single-bf16 MFMA GEMM (V, O)
__global__ __launch_bounds__(256) void cgemm_mfma(const short* __restrict__ A,
                                                  const short* __restrict__ W,
                                                  const float* __restrict__ bmag,
                                                  const float* __restrict__ bphase,
                                                  short* __restrict__ outbf,
                                                  float* __restrict__ outr,
                                                  float* __restrict__ outi,
                                                  int mode) {
    __shared__ short sA[128 * 32];
    __shared__ short sB[128 * 32];

    const int tid = threadIdx.x;
    const int w = tid >> 6, l = tid & 63;
    const int wm = w >> 1, wn = w & 1;
    const int wl = l & 15, g = l >> 4;

    int id = blockIdx.y * 32 + blockIdx.x;
    int swz = (id & 7) * 64 + (id >> 3);
    const int bm = (swz & 31) * 128;
    const int bn = (swz >> 5) * 128;

    f32x4 acc[4][4];
#pragma unroll
    for (int m = 0; m < 4; ++m)
#pragma unroll
        for (int n = 0; n < 4; ++n) acc[m][n] = (f32x4){0.f, 0.f, 0.f, 0.f};

    for (int k0 = 0; k0 < KC_; k0 += 32) {
        __syncthreads();
#pragma unroll
        for (int i = 0; i < 2; ++i) {
            int chunk = (w * 2 + i) * 64 + l;
            int row = chunk >> 2, kc = chunk & 3;
            gl_lds16(A + (size_t)(bm + row) * KC_ + k0 + kc * 8, sA + (w * 2 + i) * 64 * 8);
            gl_lds16(W + (size_t)(bn + row) * KC_ + k0 + kc * 8, sB + (w * 2 + i) * 64 * 8);
        }
        __syncthreads();

        bf16x8 af[4], bfr[4];
#pragma unroll
        for (int m = 0; m < 4; ++m)
            af[m] = *(const bf16x8*)&sA[(wm * 64 + m * 16 + wl) * 32 + g * 8];
#pragma unroll
        for (int n = 0; n < 4; ++n)
            bfr[n] = *(const bf16x8*)&sB[(wn * 64 + n * 16 + wl) * 32 + g * 8];
#pragma unroll
        for (int m = 0; m < 4; ++m)
#pragma unroll
            for (int n = 0; n < 4; ++n)
                acc[m][n] = __builtin_amdgcn_mfma_f32_16x16x32_bf16(af[m], bfr[n], acc[m][n], 0, 0, 0);
    }

#pragma unroll
    for (int n = 0; n < 4; ++n) {
        const int col = bn + wn * 64 + n * 16 + wl;
        const int ch = col & 1023;
        float sb, cb;
        sincosf(bphase[ch], &sb, &cb);
        const float bias = bmag[ch] * (col < 1024 ? cb : sb);
#pragma unroll
        for (int m = 0; m < 4; ++m) {
#pragma unroll
            for (int r = 0; r < 4; ++r) {
                const int row = bm + wm * 64 + m * 16 + g * 4 + r;
                const float v = acc[m][n][r] + bias;
                if (mode == 0) {
                    const int hh = ch >> 6, d = ch & 63;
                    outbf[(size_t)row * KC_ + hh * 128 + d + ((col >= 1024) ? 64 : 0)] = f2bf(v);
                } else {
                    if (col < 1024) outr[(size_t)row * E_ + col] = v;
                    else            outi[(size_t)row * E_ + (col - 1024)] = v;
                }
            }
        }
    }
}

// ---------------------------------------------------------------- MFMA flash attention
// 1D grid of 512 blocks, 512 threads (8 waves). QBLK=128, KVBLK=64.
// Block decode: h fastest (L2 reuse of geo tile), paired q-tiles for CU balance.
__global__ __launch_bounds__(512) void attn_split(const short* __restrict__ qh,
                                                  const short* __restrict__ ql,
                                                  const short* __restrict__ kh,
                                                  const short* __restrict__ kl,
                                                  const short* __restrict__ vc,
                                                  const short* __restrict__ ldb,
                                                  const float* __restrict__ dsc,
                                                  const float* __restrict__ dof,
                                                  short* __restrict__ otc) {
    __shared__ short sKh[64 * 128];       // swizzled 16B chunks
    __shared__ short sKl[64 * 128];
    __shared__ short sV[2][64 * 66];      // [comp][d][66] (V transposed)
    __shared__ short sP[8][16 * 68];      // per-wave P [qlocal][68]

    const int j = blockIdx.x;
    const int h = j & 15;
    const int idx = j >> 4;               // 0..31
    const int b = idx & 3;
    const int q4 = idx >> 2;              // 0..7
    const int qt = (q4 < 4) ? (7 - q4) : (q4 - 4);   // pairs (7,0),(6,1),(5,2),(4,3)

    const int tid = threadIdx.x;
    const int w = tid >> 6, l = tid & 63;
    const int wl = l & 15, g = l >> 4;

    const float dsch = dsc[h], dofh = dof[h];

    // Q hi/lo fragments: rows q = qt*128 + w*16 + wl
    bf16x8 aqh[4], aql[4];
    {
        const size_t qbase = ((size_t)(b * T_) + qt * 128 + w * 16 + wl) * KC_ + h * 128;
#pragma unroll
        for (int ks = 0; ks < 4; ++ks) {
            aqh[ks] = *(const bf16x8*)(qh + qbase + ks * 32 + g * 8);
            aql[ks] = *(const bf16x8*)(ql + qbase + ks * 32 + g * 8);
        }
    }

    f32x4 accR[4], accI[4];
#pragma unroll
    for (int nb = 0; nb < 4; ++nb) {
        accR[nb] = (f32x4){0.f, 0.f, 0.f, 0.f};
        accI[nb] = (f32x4){0.f, 0.f, 0.f, 0.f};
    }
    float m_run[4], l_run[4];
#pragma unroll
    for (int r = 0; r < 4; ++r) { m_run[r] = -3.0e38f; l_run[r] = 0.f; }

    const int nkt = 2 * qt + 2;
    for (int kt = 0; kt < nkt; ++kt) {
        __syncthreads();

        // stage K hi/lo: 1024 chunks over 512 threads (2 each); linear dest,
        // inverse-swizzled per-lane source
#pragma unroll
        for (int i = 0; i < 2; ++i) {
            int chunk = (w * 2 + i) * 64 + l;
            int row = chunk >> 4;
            int c8 = (chunk & 15) ^ ((row & 7) << 1);
            size_t src = ((size_t)(b * T_) + kt * 64 + row) * KC_ + h * 128 + c8 * 8;
            gl_lds16(kh + src, sKh + (w * 2 + i) * 64 * 8);
            gl_lds16(kl + src, sKl + (w * 2 + i) * 64 * 8);
        }
        // stage V transposed: lane = token; wave w covers comp = w>>2, dims [(w&3)*16, +16)
        {
            const short* vrow = vc + ((size_t)(b * T_) + kt * 64 + l) * KC_ + h * 128;
            const int comp = w >> 2;
            const int d0 = (w & 3) * 16;
#pragma unroll
            for (int half = 0; half < 2; ++half) {
                bf16x8 v8 = *(const bf16x8*)(vrow + comp * 64 + d0 + half * 8);
#pragma unroll
                for (int jj = 0; jj < 8; ++jj) sV[comp][(d0 + half * 8 + jj) * 66 + l] = v8[jj];
            }
        }
        __syncthreads();

        // QK^T split: hh + hl + lh
        f32x4 s[4];
#pragma unroll
        for (int nb = 0; nb < 4; ++nb) s[nb] = (f32x4){0.f, 0.f, 0.f, 0.f};
#pragma unroll
        for (int nb = 0; nb < 4; ++nb) {
            const int ktl = nb * 16 + wl;
#pragma unroll
            for (int ks = 0; ks < 4; ++ks) {
                const int pc8 = (ks * 4 + g) ^ ((ktl & 7) << 1);
                const bf16x8 bkh = *(const bf16x8*)&sKh[ktl * 128 + pc8 * 8];
                const bf16x8 bkl = *(const bf16x8*)&sKl[ktl * 128 + pc8 * 8];
                s[nb] = __builtin_amdgcn_mfma_f32_16x16x32_bf16(aqh[ks], bkh, s[nb], 0, 0, 0);
                s[nb] = __builtin_amdgcn_mfma_f32_16x16x32_bf16(aqh[ks], bkl, s[nb], 0, 0, 0);
                s[nb] = __builtin_amdgcn_mfma_f32_16x16x32_bf16(aql[ks], bkh, s[nb], 0, 0, 0);
            }
        }

        // scale + geo bias (bf16 table) + causal mask
        const int qg0 = qt * 128 + w * 16 + g * 4;
        const int kg0 = kt * 64;
        const bool domask = (kt >= 2 * qt);
#pragma unroll
        for (int nb = 0; nb < 4; ++nb) {
            const int kg = kg0 + nb * 16 + wl;
            const short* ldp = ldb + ((size_t)b * T_ + qg0) * T_ + kg;
#pragma unroll
            for (int r = 0; r < 4; ++r) {
                float sv = s[nb][r] * SCALE_ + dsch * bf2f(ldp[(size_t)r * T_]) + dofh;
                if (domask && kg > qg0 + r) sv = -1.0e9f;
                s[nb][r] = sv;
            }
        }

        // online softmax
#pragma unroll
        for (int r = 0; r < 4; ++r) {
            float mt = fmaxf(fmaxf(s[0][r], s[1][r]), fmaxf(s[2][r], s[3][r]));
            mt = fmaxf(mt, __shfl_xor(mt, 1));
            mt = fmaxf(mt, __shfl_xor(mt, 2));
            mt = fmaxf(mt, __shfl_xor(mt, 4));
            mt = fmaxf(mt, __shfl_xor(mt, 8));
            const float mnew = fmaxf(m_run[r], mt);
            const float sc = __expf(m_run[r] - mnew);
            m_run[r] = mnew;
            float rs = 0.f;
#pragma unroll
            for (int nb = 0; nb < 4; ++nb) {
                const float p = __expf(s[nb][r] - mnew);
                s[nb][r] = p;
                rs += p;
            }
            rs += __shfl_xor(rs, 1);
            rs += __shfl_xor(rs, 2);
            rs += __shfl_xor(rs, 4);
            rs += __shfl_xor(rs, 8);
            l_run[r] = l_run[r] * sc + rs;
#pragma unroll
            for (int nb = 0; nb < 4; ++nb) { accR[nb][r] *= sc; accI[nb][r] *= sc; }
        }

        // P -> LDS (wave-private), then PV
#pragma unroll
        for (int nb = 0; nb < 4; ++nb)
#pragma unroll
            for (int r = 0; r < 4; ++r)
                sP[w][(g * 4 + r) * 68 + nb * 16 + wl] = f2bf(s[nb][r]);

        bf16x8 ap[2];
#pragma unroll
        for (int ks = 0; ks < 2; ++ks)
            ap[ks] = *(const bf16x8*)&sP[w][wl * 68 + ks * 32 + g * 8];
#pragma unroll
        for (int nb = 0; nb < 4; ++nb) {
#pragma unroll
            for (int ks = 0; ks < 2; ++ks) {
                const bf16x8 bvr = *(const bf16x8*)&sV[0][(nb * 16 + wl) * 66 + ks * 32 + g * 8];
                const bf16x8 bvi = *(const bf16x8*)&sV[1][(nb * 16 + wl) * 66 + ks * 32 + g * 8];
                accR[nb] = __builtin_amdgcn_mfma_f32_16x16x32_bf16(ap[ks], bvr, accR[nb], 0, 0, 0);
                accI[nb] = __builtin_amdgcn_mfma_f32_16x16x32_bf16(ap[ks], bvi, accI[nb], 0, 0, 0);
            }
        }
    }

    // epilogue
    float inv[4];
#pragma unroll
    for (int r = 0; r < 4; ++r) inv[r] = 1.0f / l_run[r];
#pragma unroll
    for (int nb = 0; nb < 4; ++nb) {
#pragma unroll
        for (int r = 0; r < 4; ++r) {
            const int q = qt * 128 + w * 16 + g * 4 + r;
            const int d = nb * 16 + wl;
            const size_t base = ((size_t)(b * T_) + q) * KC_ + h * 64 + d;
            otc[base] = f2bf(accR[nb][r] * inv[r]);
            otc[base + 1024] = f2bf(accI[nb][r] * inv[r]);
        }
    }
}

// ---------------------------------------------------------------- launch
extern "C" void kernel_launch(void* const* d_in, const int* in_sizes, int n_in,
                              void* d_out, int out_size, void* d_ws, size_t ws_size,
                              hipStream_t stream) {
    const float* x_r  = (const float*)d_in[0];
    const float* x_i  = (const float*)d_in[1];
    const float* lat  = (const float*)d_in[2];
    const float* lon  = (const float*)d_in[3];
    const float* q_lm = (const float*)d_in[4];
    const float* q_ph = (const float*)d_in[5];
    const float* q_bm = (const float*)d_in[6];
    const float* q_bp = (const float*)d_in[7];
    const float* k_lm = (const float*)d_in[8];
    const float* k_ph = (const float*)d_in[9];
    const float* k_bm = (const float*)d_in[10];
    const float* k_bp = (const float*)d_in[11];
    const float* v_lm = (const float*)d_in[12];
    const float* v_ph = (const float*)d_in[13];
    const float* v_bm = (const float*)d_in[14];
    const float* v_bp = (const float*)d_in[15];
    const float* o_lm = (const float*)d_in[16];
    const float* o_ph = (const float*)d_in[17];
    const float* o_bm = (const float*)d_in[18];
    const float* o_bp = (const float*)d_in[19];
    const float* dsc  = (const float*)d_in[20];
    const float* dof  = (const float*)d_in[21];

    char* ws = (char*)d_ws;
    const size_t MB = 1024u * 1024u;
    short* Wv  = (short*)(ws + 0 * MB);     // 8 MB
    short* Wo  = (short*)(ws + 8 * MB);     // 8 MB
    short* Wqh = (short*)(ws + 16 * MB);    // 8 MB
    short* Wql = (short*)(ws + 24 * MB);
    short* Wkh = (short*)(ws + 32 * MB);
    short* Wkl = (short*)(ws + 40 * MB);
    short* xch = (short*)(ws + 48 * MB);    // 16 MB
    short* xcl = (short*)(ws + 64 * MB);    // 16 MB
    short* qhh = (short*)(ws + 80 * MB);    // 16 MB
    short* qll = (short*)(ws + 96 * MB);
    short* khh = (short*)(ws + 112 * MB);
    short* kll = (short*)(ws + 128 * MB);
    short* vcb = (short*)(ws + 144 * MB);   // 16 MB
    short* otc = (short*)(ws + 160 * MB);   // 16 MB
    short* ldt = (short*)(ws + 176 * MB);   // B*T*T bf16, 8 MB

    wgen_split<<<(E_ * E_) / 256, 256, 0, stream>>>(q_lm, q_ph, Wqh, Wql);
    wgen_split<<<(E_ * E_) / 256, 256, 0, stream>>>(k_lm, k_ph, Wkh, Wkl);
    wgen<<<(E_ * E_) / 256, 256, 0, stream>>>(v_lm, v_ph, Wv);
    wgen<<<(E_ * E_) / 256, 256, 0, stream>>>(o_lm, o_ph, Wo);
    xcat_split<<<BTE / 256, 256, 0, stream>>>(x_r, x_i, xch, xcl);
    geodist<<<BTT / 256, 256, 0, stream>>>(lat, lon, ldt);

    dim3 ggrid(M_ / 128, KC_ / 128);
    cgemm_qk<<<ggrid, 256, 0, stream>>>(xch, xcl, Wqh, Wql, q_bm, q_bp, qhh, qll);
    cgemm_qk<<<ggrid, 256, 0, stream>>>(xch, xcl, Wkh, Wkl, k_bm, k_bp, khh, kll);
    cgemm_mfma<<<ggrid, 256, 0, stream>>>(xch, Wv, v_bm, v_bp, vcb, nullptr, nullptr, 0);

    attn_split<<<512, 512, 0, stream>>>(qhh, qll, khh, kll, vcb, ldt, dsc, dof, otc);

    float* yr = (float*)d_out;
    float* yi = (float*)d_out + BTE;
    cgemm_mfma<<<ggrid, 256, 0, stream>>>(otc, Wo, o_bm, o_bp, nullptr, yr, yi, 1);
}

// Round 5
// 601.803 us; speedup vs baseline: 4.2128x; 1.0789x over previous
//
#include <hip/hip_runtime.h>
#include <math.h>

#define B_ 4
#define T_ 1024
#define E_ 1024
#define H_ 16
#define HD_ 64

constexpr float SCALE_ = 0.125f;              // HD^-0.5
constexpr float PI_F = 3.14159265358979323846f;

constexpr size_t BTE = (size_t)B_ * T_ * E_;  // 4M
constexpr size_t BTT = (size_t)B_ * T_ * T_;  // 4M
constexpr int M_ = B_ * T_;                   // 4096
constexpr int KC_ = 2 * E_;                   // 2048 (concat r|i)

typedef __attribute__((ext_vector_type(8))) short bf16x8;
typedef __attribute__((ext_vector_type(4))) float f32x4;

__device__ __forceinline__ short f2bf(float f) {
    unsigned int u = __float_as_uint(f);
    unsigned int r = (u + 0x7fffu + ((u >> 16) & 1u)) >> 16;
    return (short)r;
}
__device__ __forceinline__ float bf2f(short s) {
    return __uint_as_float(((unsigned int)(unsigned short)s) << 16);
}
__device__ __forceinline__ void fsplit(float v, short& h, short& l) {
    short hh = f2bf(v);
    h = hh;
    l = f2bf(v - bf2f(hh));
}
__device__ __forceinline__ void gl_lds16(const void* g, void* l) {
    __builtin_amdgcn_global_load_lds(
        (const __attribute__((address_space(1))) unsigned int*)g,
        (__attribute__((address_space(3))) unsigned int*)l, 16, 0, 0);
}

// ---------------------------------------------------------------- stacked bf16 weights (single)
__global__ __launch_bounds__(256) void wgen(const float* __restrict__ lm,
                                            const float* __restrict__ ph,
                                            short* __restrict__ W) {
    int idx = blockIdx.x * 256 + threadIdx.x;   // over E*E
    int n = idx >> 10, k = idx & 1023;
    float m = expf(lm[idx]);
    float s, c;
    sincosf(ph[idx], &s, &c);
    float wr = m * c, wi = m * s;
    size_t r0 = (size_t)n * KC_;
    size_t r1 = (size_t)(n + 1024) * KC_;
    W[r0 + k]        = f2bf(wr);
    W[r0 + 1024 + k] = f2bf(-wi);
    W[r1 + k]        = f2bf(wi);
    W[r1 + 1024 + k] = f2bf(wr);
}

// ---------------------------------------------------------------- stacked bf16 weights (hi/lo split)
__global__ __launch_bounds__(256) void wgen_split(const float* __restrict__ lm,
                                                  const float* __restrict__ ph,
                                                  short* __restrict__ Wh,
                                                  short* __restrict__ Wl) {
    int idx = blockIdx.x * 256 + threadIdx.x;
    int n = idx >> 10, k = idx & 1023;
    float m = expf(lm[idx]);
    float s, c;
    sincosf(ph[idx], &s, &c);
    float wr = m * c, wi = m * s;
    size_t o0 = (size_t)n * KC_ + k;
    size_t o1 = (size_t)n * KC_ + 1024 + k;
    size_t o2 = (size_t)(n + 1024) * KC_ + k;
    size_t o3 = (size_t)(n + 1024) * KC_ + 1024 + k;
    short h, l;
    fsplit(wr,  h, l); Wh[o0] = h; Wl[o0] = l;
    fsplit(-wi, h, l); Wh[o1] = h; Wl[o1] = l;
    fsplit(wi,  h, l); Wh[o2] = h; Wl[o2] = l;
    fsplit(wr,  h, l); Wh[o3] = h; Wl[o3] = l;
}

// ---------------------------------------------------------------- x concat -> bf16 hi/lo
__global__ __launch_bounds__(256) void xcat_split(const float* __restrict__ xr,
                                                  const float* __restrict__ xi,
                                                  short* __restrict__ xh,
                                                  short* __restrict__ xl) {
    size_t idx = (size_t)blockIdx.x * 256 + threadIdx.x;  // BTE
    size_t m = idx >> 10, k = idx & 1023;
    short h, l;
    fsplit(xr[idx], h, l);
    xh[m * KC_ + k] = h; xl[m * KC_ + k] = l;
    fsplit(xi[idx], h, l);
    xh[m * KC_ + 1024 + k] = h; xl[m * KC_ + 1024 + k] = l;
}

// ---------------------------------------------------------------- geodesic bias table (bf16)
__global__ __launch_bounds__(256) void geodist(const float* __restrict__ lat,
                                               const float* __restrict__ lon,
                                               short* __restrict__ ld) {
    size_t idx = (size_t)blockIdx.x * 256 + threadIdx.x;   // over B*T*T
    int k = (int)(idx & (T_ - 1));
    int q = (int)((idx >> 10) & (T_ - 1));
    int b = (int)(idx >> 20);
    float la1 = (lat[b * T_ + q] - 90.f) * (PI_F / 180.f);
    float la2 = (lat[b * T_ + k] - 90.f) * (PI_F / 180.f);
    float lo1 = lon[b * T_ + q] * (PI_F / 180.f);
    float lo2 = lon[b * T_ + k] * (PI_F / 180.f);
    float sdla = sinf((la2 - la1) * 0.5f);
    float sdlo = sinf((lo2 - lo1) * 0.5f);
    float a = sdla * sdla + cosf(la1) * cosf(la2) * sdlo * sdlo;
    a = fminf(fmaxf(a, 0.f), 1.f);
    float dd = 2.f * asinf(sqrtf(a)) * (180.f / PI_F);
    ld[idx] = f2bf(log1pf(dd));
}

// ---------------------------------------------------------------- fused split-bf16 Q+K GEMM + RoPE
// A is shared; 3 LDS buffers, each [128 rows][8 chunks of 16B], chunks 0-3 = hi, 4-7 = lo.
// XOR swizzle: physical chunk cp holds logical c8 = cp ^ (row&7) -> 2-way (free) ds_read_b128.
__global__ __launch_bounds__(256) void cgemm_qk2(const short* __restrict__ Ah,
                                                 const short* __restrict__ Al,
                                                 const short* __restrict__ Qwh,
                                                 const short* __restrict__ Qwl,
                                                 const short* __restrict__ Kwh,
                                                 const short* __restrict__ Kwl,
                                                 const float* __restrict__ qbm,
                                                 const float* __restrict__ qbp,
                                                 const float* __restrict__ kbm,
                                                 const float* __restrict__ kbp,
                                                 short* __restrict__ Qh,
                                                 short* __restrict__ Ql,
                                                 short* __restrict__ Kh,
                                                 short* __restrict__ Kl) {
    __shared__ short sA[128 * 64];
    __shared__ short sQ[128 * 64];
    __shared__ short sK[128 * 64];

    const int tid = threadIdx.x;
    const int w = tid >> 6, l = tid & 63;
    const int wm = w >> 1, wn = w & 1;
    const int wl = l & 15, g = l >> 4;

    int id = blockIdx.y * 32 + blockIdx.x;     // nwg = 512
    int swz = (id & 7) * 64 + (id >> 3);
    const int bm = (swz & 31) * 128;
    const int bn = (swz >> 5) * 128;

    f32x4 accQ[4][4], accK[4][4];
#pragma unroll
    for (int m = 0; m < 4; ++m)
#pragma unroll
        for (int n = 0; n < 4; ++n) {
            accQ[m][n] = (f32x4){0.f, 0.f, 0.f, 0.f};
            accK[m][n] = (f32x4){0.f, 0.f, 0.f, 0.f};
        }

    for (int k0 = 0; k0 < KC_; k0 += 32) {
        __syncthreads();
#pragma unroll
        for (int i = 0; i < 4; ++i) {
            const int chunk = (w * 4 + i) * 64 + l;   // 0..1023
            const int row = chunk >> 3;
            const int c8 = (chunk & 7) ^ (row & 7);   // logical chunk (involution)
            const size_t ca = (size_t)(bm + row) * KC_ + k0 + (c8 & 3) * 8;
            const size_t cb = (size_t)(bn + row) * KC_ + k0 + (c8 & 3) * 8;
            gl_lds16(((c8 < 4) ? Ah : Al) + ca, sA + (size_t)(w * 4 + i) * 64 * 8);
            gl_lds16(((c8 < 4) ? Qwh : Qwl) + cb, sQ + (size_t)(w * 4 + i) * 64 * 8);
            gl_lds16(((c8 < 4) ? Kwh : Kwl) + cb, sK + (size_t)(w * 4 + i) * 64 * 8);
        }
        __syncthreads();

        bf16x8 afh[4], afl[4];
#pragma unroll
        for (int m = 0; m < 4; ++m) {
            const int ra = wm * 64 + m * 16 + wl;
            const int sw = ra & 7;
            afh[m] = *(const bf16x8*)&sA[(ra * 8 + (g ^ sw)) * 8];
            afl[m] = *(const bf16x8*)&sA[(ra * 8 + ((g + 4) ^ sw)) * 8];
        }
#pragma unroll
        for (int n = 0; n < 4; ++n) {
            const int rb = wn * 64 + n * 16 + wl;
            const int sw = rb & 7;
            const bf16x8 qh_ = *(const bf16x8*)&sQ[(rb * 8 + (g ^ sw)) * 8];
            const bf16x8 ql_ = *(const bf16x8*)&sQ[(rb * 8 + ((g + 4) ^ sw)) * 8];
            const bf16x8 kh_ = *(const bf16x8*)&sK[(rb * 8 + (g ^ sw)) * 8];
            const bf16x8 kl_ = *(const bf16x8*)&sK[(rb * 8 + ((g + 4) ^ sw)) * 8];
#pragma unroll
            for (int m = 0; m < 4; ++m) {
                accQ[m][n] = __builtin_amdgcn_mfma_f32_16x16x32_bf16(afh[m], qh_, accQ[m][n], 0, 0, 0);
                accQ[m][n] = __builtin_amdgcn_mfma_f32_16x16x32_bf16(afh[m], ql_, accQ[m][n], 0, 0, 0);
                accQ[m][n] = __builtin_amdgcn_mfma_f32_16x16x32_bf16(afl[m], qh_, accQ[m][n], 0, 0, 0);
                accK[m][n] = __builtin_amdgcn_mfma_f32_16x16x32_bf16(afh[m], kh_, accK[m][n], 0, 0, 0);
                accK[m][n] = __builtin_amdgcn_mfma_f32_16x16x32_bf16(afh[m], kl_, accK[m][n], 0, 0, 0);
                accK[m][n] = __builtin_amdgcn_mfma_f32_16x16x32_bf16(afl[m], kh_, accK[m][n], 0, 0, 0);
            }
        }
    }

    // bias add (Q and K)
#pragma unroll
    for (int n = 0; n < 4; ++n) {
        const int col = bn + wn * 64 + n * 16 + wl;
        const int ch = col & 1023;
        float qs, qc, ks, kc;
        sincosf(qbp[ch], &qs, &qc);
        sincosf(kbp[ch], &ks, &kc);
        const float qbias = qbm[ch] * (col < 1024 ? qc : qs);
        const float kbias = kbm[ch] * (col < 1024 ? kc : ks);
#pragma unroll
        for (int m = 0; m < 4; ++m)
#pragma unroll
            for (int r = 0; r < 4; ++r) {
                accQ[m][n][r] += qbias;
                accK[m][n][r] += kbias;
            }
    }

    // fused RoPE: pairs (n, n+2); freq j = n*16+wl; same angle for Q and K
#pragma unroll
    for (int n = 0; n < 2; ++n) {
        const int j = n * 16 + wl;
        const float invf = expf(-(2.f * j / 64.f) * 9.210340371976184f);
#pragma unroll
        for (int m = 0; m < 4; ++m)
#pragma unroll
            for (int r = 0; r < 4; ++r) {
                const int row = bm + wm * 64 + m * 16 + g * 4 + r;
                const float th = (float)(row & 1023) * invf;
                float s_, c_;
                sincosf(th, &s_, &c_);
                float x1 = accQ[m][n][r], x2 = accQ[m][n + 2][r];
                accQ[m][n][r]     = x1 * c_ - x2 * s_;
                accQ[m][n + 2][r] = x2 * c_ + x1 * s_;
                x1 = accK[m][n][r]; x2 = accK[m][n + 2][r];
                accK[m][n][r]     = x1 * c_ - x2 * s_;
                accK[m][n + 2][r] = x2 * c_ + x1 * s_;
            }
    }

    // split store, head-concat layout
#pragma unroll
    for (int n = 0; n < 4; ++n) {
        const int col = bn + wn * 64 + n * 16 + wl;
        const int ch = col & 1023;
        const int off = (ch >> 6) * 128 + (ch & 63) + ((col >= 1024) ? 64 : 0);
#pragma unroll
        for (int m = 0; m < 4; ++m)
#pragma unroll
            for (int r = 0; r < 4; ++r) {
                const int row = bm + wm * 64 + m * 16 + g * 4 + r;
                short h_, l_;
                fsplit(accQ[m][n][r], h_, l_);
                Qh[(size_t)row * KC_ + off] = h_;
                Ql[(size_t)row * KC_ + off] = l_;
                fsplit(accK[m][n][r], h_, l_);
                Kh[(size_t)row * KC_ + off] = h_;
                Kl[(size_t)row * KC_ + off] = l_;
            }
    }
}

// ---------------------------------------------------------------- single-bf16 MFMA GEMM (V, O)
// One interleaved LDS buffer [128 rows][8 chunks]: chunks 0-3 = A row, 4-7 = W row; XOR swizzle.
__global__ __launch_bounds__(256) void cgemm_mfma(const short* __restrict__ A,
                                                  const short* __restrict__ W,
                                                  const float* __restrict__ bmag,
                                                  const float* __restrict__ bphase,
                                                  short* __restrict__ outbf,
                                                  float* __restrict__ outr,
                                                  float* __restrict__ outi,
                                                  int mode) {
    __shared__ short sAB[128 * 64];

    const int tid = threadIdx.x;
    const int w = tid >> 6, l = tid & 63;
    const int wm = w >> 1, wn = w & 1;
    const int wl = l & 15, g = l >> 4;

    int id = blockIdx.y * 32 + blockIdx.x;
    int swz = (id & 7) * 64 + (id >> 3);
    const int bm = (swz & 31) * 128;
    const int bn = (swz >> 5) * 128;

    f32x4 acc[4][4];
#pragma unroll
    for (int m = 0; m < 4; ++m)
#pragma unroll
        for (int n = 0; n < 4; ++n) acc[m][n] = (f32x4){0.f, 0.f, 0.f, 0.f};

    for (int k0 = 0; k0 < KC_; k0 += 32) {
        __syncthreads();
#pragma unroll
        for (int i = 0; i < 4; ++i) {
            const int chunk = (w * 4 + i) * 64 + l;
            const int row = chunk >> 3;
            const int c8 = (chunk & 7) ^ (row & 7);
            const short* src = (c8 < 4)
                ? A + (size_t)(bm + row) * KC_ + k0 + (c8 & 3) * 8
                : W + (size_t)(bn + row) * KC_ + k0 + (c8 & 3) * 8;
            gl_lds16(src, sAB + (size_t)(w * 4 + i) * 64 * 8);
        }
        __syncthreads();

        bf16x8 af[4], bfr[4];
#pragma unroll
        for (int m = 0; m < 4; ++m) {
            const int ra = wm * 64 + m * 16 + wl;
            af[m] = *(const bf16x8*)&sAB[(ra * 8 + (g ^ (ra & 7))) * 8];
        }
#pragma unroll
        for (int n = 0; n < 4; ++n) {
            const int rb = wn * 64 + n * 16 + wl;
            bfr[n] = *(const bf16x8*)&sAB[(rb * 8 + ((g + 4) ^ (rb & 7))) * 8];
        }
#pragma unroll
        for (int m = 0; m < 4; ++m)
#pragma unroll
            for (int n = 0; n < 4; ++n)
                acc[m][n] = __builtin_amdgcn_mfma_f32_16x16x32_bf16(af[m], bfr[n], acc[m][n], 0, 0, 0);
    }

#pragma unroll
    for (int n = 0; n < 4; ++n) {
        const int col = bn + wn * 64 + n * 16 + wl;
        const int ch = col & 1023;
        float sb, cb;
        sincosf(bphase[ch], &sb, &cb);
        const float bias = bmag[ch] * (col < 1024 ? cb : sb);
#pragma unroll
        for (int m = 0; m < 4; ++m) {
#pragma unroll
            for (int r = 0; r < 4; ++r) {
                const int row = bm + wm * 64 + m * 16 + g * 4 + r;
                const float v = acc[m][n][r] + bias;
                if (mode == 0) {
                    const int hh = ch >> 6, d = ch & 63;
                    outbf[(size_t)row * KC_ + hh * 128 + d + ((col >= 1024) ? 64 : 0)] = f2bf(v);
                } else {
                    if (col < 1024) outr[(size_t)row * E_ + col] = v;
                    else            outi[(size_t)row * E_ + (col - 1024)] = v;
                }
            }
        }
    }
}

// ---------------------------------------------------------------- MFMA flash attention
// 1D grid of 512 blocks, 512 threads (8 waves). QBLK=128, KVBLK=64.
__global__ __launch_bounds__(512) void attn_split(const short* __restrict__ qh,
                                                  const short* __restrict__ ql,
                                                  const short* __restrict__ kh,
                                                  const short* __restrict__ kl,
                                                  const short* __restrict__ vc,
                                                  const short* __restrict__ ldb,
                                                  const float* __restrict__ dsc,
                                                  const float* __restrict__ dof,
                                                  short* __restrict__ otc) {
    __shared__ short sKh[64 * 128];       // swizzled 16B chunks (full 4-bit XOR)
    __shared__ short sKl[64 * 128];
    __shared__ short sV[2][64 * 66];      // [comp][d][66] (V transposed)
    __shared__ short sP[8][16 * 68];      // per-wave P [qlocal][68]

    const int j = blockIdx.x;
    const int h = j & 15;
    const int idx = j >> 4;               // 0..31
    const int b = idx & 3;
    const int q4 = idx >> 2;              // 0..7
    const int qt = (q4 < 4) ? (7 - q4) : (q4 - 4);   // pairs (7,0),(6,1),(5,2),(4,3)

    const int tid = threadIdx.x;
    const int w = tid >> 6, l = tid & 63;
    const int wl = l & 15, g = l >> 4;

    const float dsch = dsc[h], dofh = dof[h];

    // Q hi/lo fragments: rows q = qt*128 + w*16 + wl
    bf16x8 aqh[4], aql[4];
    {
        const size_t qbase = ((size_t)(b * T_) + qt * 128 + w * 16 + wl) * KC_ + h * 128;
#pragma unroll
        for (int ks = 0; ks < 4; ++ks) {
            aqh[ks] = *(const bf16x8*)(qh + qbase + ks * 32 + g * 8);
            aql[ks] = *(const bf16x8*)(ql + qbase + ks * 32 + g * 8);
        }
    }

    f32x4 accR[4], accI[4];
#pragma unroll
    for (int nb = 0; nb < 4; ++nb) {
        accR[nb] = (f32x4){0.f, 0.f, 0.f, 0.f};
        accI[nb] = (f32x4){0.f, 0.f, 0.f, 0.f};
    }
    float m_run[4], l_run[4];
#pragma unroll
    for (int r = 0; r < 4; ++r) { m_run[r] = -3.0e38f; l_run[r] = 0.f; }

    const int nkt = 2 * qt + 2;
    for (int kt = 0; kt < nkt; ++kt) {
        __syncthreads();

        // stage K hi/lo: linear dest, inverse-swizzled per-lane source (4-bit XOR)
#pragma unroll
        for (int i = 0; i < 2; ++i) {
            int chunk = (w * 2 + i) * 64 + l;
            int row = chunk >> 4;
            int c8 = (chunk & 15) ^ (row & 15);
            size_t src = ((size_t)(b * T_) + kt * 64 + row) * KC_ + h * 128 + c8 * 8;
            gl_lds16(kh + src, sKh + (w * 2 + i) * 64 * 8);
            gl_lds16(kl + src, sKl + (w * 2 + i) * 64 * 8);
        }
        // stage V transposed: lane = token; wave w covers comp = w>>2, dims [(w&3)*16, +16)
        {
            const short* vrow = vc + ((size_t)(b * T_) + kt * 64 + l) * KC_ + h * 128;
            const int comp = w >> 2;
            const int d0 = (w & 3) * 16;
#pragma unroll
            for (int half = 0; half < 2; ++half) {
                bf16x8 v8 = *(const bf16x8*)(vrow + comp * 64 + d0 + half * 8);
#pragma unroll
                for (int jj = 0; jj < 8; ++jj) sV[comp][(d0 + half * 8 + jj) * 66 + l] = v8[jj];
            }
        }
        __syncthreads();

        // QK^T split: hh + hl + lh
        f32x4 s[4];
#pragma unroll
        for (int nb = 0; nb < 4; ++nb) s[nb] = (f32x4){0.f, 0.f, 0.f, 0.f};
#pragma unroll
        for (int nb = 0; nb < 4; ++nb) {
            const int ktl = nb * 16 + wl;
#pragma unroll
            for (int ks = 0; ks < 4; ++ks) {
                const int pc8 = (ks * 4 + g) ^ (ktl & 15);
                const bf16x8 bkh = *(const bf16x8*)&sKh[ktl * 128 + pc8 * 8];
                const bf16x8 bkl = *(const bf16x8*)&sKl[ktl * 128 + pc8 * 8];
                s[nb] = __builtin_amdgcn_mfma_f32_16x16x32_bf16(aqh[ks], bkh, s[nb], 0, 0, 0);
                s[nb] = __builtin_amdgcn_mfma_f32_16x16x32_bf16(aqh[ks], bkl, s[nb], 0, 0, 0);
                s[nb] = __builtin_amdgcn_mfma_f32_16x16x32_bf16(aql[ks], bkh, s[nb], 0, 0, 0);
            }
        }

        // scale + geo bias (bf16 table) + causal mask
        const int qg0 = qt * 128 + w * 16 + g * 4;
        const int kg0 = kt * 64;
        const bool domask = (kt >= 2 * qt);
#pragma unroll
        for (int nb = 0; nb < 4; ++nb) {
            const int kg = kg0 + nb * 16 + wl;
            const short* ldp = ldb + ((size_t)b * T_ + qg0) * T_ + kg;
#pragma unroll
            for (int r = 0; r < 4; ++r) {
                float sv = s[nb][r] * SCALE_ + dsch * bf2f(ldp[(size_t)r * T_]) + dofh;
                if (domask && kg > qg0 + r) sv = -1.0e9f;
                s[nb][r] = sv;
            }
        }

        // online softmax
#pragma unroll
        for (int r = 0; r < 4; ++r) {
            float mt = fmaxf(fmaxf(s[0][r], s[1][r]), fmaxf(s[2][r], s[3][r]));
            mt = fmaxf(mt, __shfl_xor(mt, 1));
            mt = fmaxf(mt, __shfl_xor(mt, 2));
            mt = fmaxf(mt, __shfl_xor(mt, 4));
            mt = fmaxf(mt, __shfl_xor(mt, 8));
            const float mnew = fmaxf(m_run[r], mt);
            const float sc = __expf(m_run[r] - mnew);
            m_run[r] = mnew;
            float rs = 0.f;
#pragma unroll
            for (int nb = 0; nb < 4; ++nb) {
                const float p = __expf(s[nb][r] - mnew);
                s[nb][r] = p;
                rs += p;
            }
            rs += __shfl_xor(rs, 1);
            rs += __shfl_xor(rs, 2);
            rs += __shfl_xor(rs, 4);
            rs += __shfl_xor(rs, 8);
            l_run[r] = l_run[r] * sc + rs;
#pragma unroll
            for (int nb = 0; nb < 4; ++nb) { accR[nb][r] *= sc; accI[nb][r] *= sc; }
        }

        // P -> LDS (wave-private), then PV
#pragma unroll
        for (int nb = 0; nb < 4; ++nb)
#pragma unroll
            for (int r = 0; r < 4; ++r)
                sP[w][(g * 4 + r) * 68 + nb * 16 + wl] = f2bf(s[nb][r]);

        bf16x8 ap[2];
#pragma unroll
        for (int ks = 0; ks < 2; ++ks)
            ap[ks] = *(const bf16x8*)&sP[w][wl * 68 + ks * 32 + g * 8];
#pragma unroll
        for (int nb = 0; nb < 4; ++nb) {
#pragma unroll
            for (int ks = 0; ks < 2; ++ks) {
                const bf16x8 bvr = *(const bf16x8*)&sV[0][(nb * 16 + wl) * 66 + ks * 32 + g * 8];
                const bf16x8 bvi = *(const bf16x8*)&sV[1][(nb * 16 + wl) * 66 + ks * 32 + g * 8];
                accR[nb] = __builtin_amdgcn_mfma_f32_16x16x32_bf16(ap[ks], bvr, accR[nb], 0, 0, 0);
                accI[nb] = __builtin_amdgcn_mfma_f32_16x16x32_bf16(ap[ks], bvi, accI[nb], 0, 0, 0);
            }
        }
    }

    // epilogue
    float inv[4];
#pragma unroll
    for (int r = 0; r < 4; ++r) inv[r] = 1.0f / l_run[r];
#pragma unroll
    for (int nb = 0; nb < 4; ++nb) {
#pragma unroll
        for (int r = 0; r < 4; ++r) {
            const int q = qt * 128 + w * 16 + g * 4 + r;
            const int d = nb * 16 + wl;
            const size_t base = ((size_t)(b * T_) + q) * KC_ + h * 64 + d;
            otc[base] = f2bf(accR[nb][r] * inv[r]);
            otc[base + 1024] = f2bf(accI[nb][r] * inv[r]);
        }
    }
}

// ---------------------------------------------------------------- launch
extern "C" void kernel_launch(void* const* d_in, const int* in_sizes, int n_in,
                              void* d_out, int out_size, void* d_ws, size_t ws_size,
                              hipStream_t stream) {
    const float* x_r  = (const float*)d_in[0];
    const float* x_i  = (const float*)d_in[1];
    const float* lat  = (const float*)d_in[2];
    const float* lon  = (const float*)d_in[3];
    const float* q_lm = (const float*)d_in[4];
    const float* q_ph = (const float*)d_in[5];
    const float* q_bm = (const float*)d_in[6];
    const float* q_bp = (const float*)d_in[7];
    const float* k_lm = (const float*)d_in[8];
    const float* k_ph = (const float*)d_in[9];
    const float* k_bm = (const float*)d_in[10];
    const float* k_bp = (const float*)d_in[11];
    const float* v_lm = (const float*)d_in[12];
    const float* v_ph = (const float*)d_in[13];
    const float* v_bm = (const float*)d_in[14];
    const float* v_bp = (const float*)d_in[15];
    const float* o_lm = (const float*)d_in[16];
    const float* o_ph = (const float*)d_in[17];
    const float* o_bm = (const float*)d_in[18];
    const float* o_bp = (const float*)d_in[19];
    const float* dsc  = (const float*)d_in[20];
    const float* dof  = (const float*)d_in[21];

    char* ws = (char*)d_ws;
    const size_t MB = 1024u * 1024u;
    short* Wv  = (short*)(ws + 0 * MB);     // 8 MB
    short* Wo  = (short*)(ws + 8 * MB);     // 8 MB
    short* Wqh = (short*)(ws + 16 * MB);    // 8 MB
    short* Wql = (short*)(ws + 24 * MB);
    short* Wkh = (short*)(ws + 32 * MB);
    short* Wkl = (short*)(ws + 40 * MB);
    short* xch = (short*)(ws + 48 * MB);    // 16 MB
    short* xcl = (short*)(ws + 64 * MB);    // 16 MB
    short* qhh = (short*)(ws + 80 * MB);    // 16 MB
    short* qll = (short*)(ws + 96 * MB);
    short* khh = (short*)(ws + 112 * MB);
    short* kll = (short*)(ws + 128 * MB);
    short* vcb = (short*)(ws + 144 * MB);   // 16 MB
    short* otc = (short*)(ws + 160 * MB);   // 16 MB
    short* ldt = (short*)(ws + 176 * MB);   // B*T*T bf16, 8 MB

    wgen_split<<<(E_ * E_) / 256, 256, 0, stream>>>(q_lm, q_ph, Wqh, Wql);
    wgen_split<<<(E_ * E_) / 256, 256, 0, stream>>>(k_lm, k_ph, Wkh, Wkl);
    wgen<<<(E_ * E_) / 256, 256, 0, stream>>>(v_lm, v_ph, Wv);
    wgen<<<(E_ * E_) / 256, 256, 0, stream>>>(o_lm, o_ph, Wo);
    xcat_split<<<BTE / 256, 256, 0, stream>>>(x_r, x_i, xch, xcl);
    geodist<<<BTT / 256, 256, 0, stream>>>(lat, lon, ldt);

    dim3 ggrid(M_ / 128, KC_ / 128);
    cgemm_qk2<<<ggrid, 256, 0, stream>>>(xch, xcl, Wqh, Wql, Wkh, Wkl,
                                         q_bm, q_bp, k_bm, k_bp,
                                         qhh, qll, khh, kll);
    cgemm_mfma<<<ggrid, 256, 0, stream>>>(xch, Wv, v_bm, v_bp, vcb, nullptr, nullptr, 0);

    attn_split<<<512, 512, 0, stream>>>(qhh, qll, khh, kll, vcb, ldt, dsc, dof, otc);

    float* yr = (float*)d_out;
    float* yi = (float*)d_out + BTE;
    cgemm_mfma<<<ggrid, 256, 0, stream>>>(otc, Wo, o_bm, o_bp, nullptr, yr, yi, 1);
}